// Round 2
// baseline (6256.087 us; speedup 1.0000x reference)
//
#include <hip/hip_runtime.h>
#include <hip/hip_bf16.h>

typedef __hip_bfloat16 bf16;

// ---------- helpers ----------
__device__ __forceinline__ float b2f_us(unsigned short u) {
    union { unsigned int i; float f; } c;
    c.i = ((unsigned int)u) << 16;
    return c.f;
}
__device__ __forceinline__ unsigned short f2b_us(float f) {
    bf16 h = __float2bfloat16(f);
    return *reinterpret_cast<unsigned short*>(&h);
}
__device__ __forceinline__ void unpack8(uint4 p, float* f) {
    f[0] = b2f_us(p.x & 0xffff); f[1] = b2f_us(p.x >> 16);
    f[2] = b2f_us(p.y & 0xffff); f[3] = b2f_us(p.y >> 16);
    f[4] = b2f_us(p.z & 0xffff); f[5] = b2f_us(p.z >> 16);
    f[6] = b2f_us(p.w & 0xffff); f[7] = b2f_us(p.w >> 16);
}

// ---------- degree / dinv ----------
__global__ __launch_bounds__(256) void k_count(const int* __restrict__ col,
                                               float* __restrict__ deg, int E) {
    int e = blockIdx.x * 256 + threadIdx.x;
    if (e < E) atomicAdd(deg + col[e], 1.0f);
}
__global__ __launch_bounds__(256) void k_rsqrt(float* __restrict__ d, int N) {
    int i = blockIdx.x * 256 + threadIdx.x;
    if (i < N) d[i] = rsqrtf(d[i] + 1.0f);  // +1 self-loop
}

// ---------- layer-1 GEMM: [N,3] @ [3,64], f32 in, bf16 out ----------
__global__ __launch_bounds__(256) void k_gemm1(const float* __restrict__ x,
                                               const float* __restrict__ W,
                                               bf16* __restrict__ xw, int M) {
    __shared__ float w[192];
    int t = threadIdx.x;
    if (t < 192) w[t] = W[t];
    __syncthreads();
    int idx = blockIdx.x * 256 + t;  // over M*64
    if (idx < M * 64) {
        int n = idx >> 6, f = idx & 63;
        float x0 = x[n * 3 + 0];
        float x1 = x[n * 3 + 1];
        float x2 = x[n * 3 + 2];
        float acc = x0 * w[f] + x1 * w[64 + f] + x2 * w[128 + f];
        xw[idx] = __float2bfloat16(acc);
    }
}

// ---------- tiled GEMM: A[M,K](bf16) @ B[K,N](f32) -> C[M,N](bf16), f32 acc
// Requires M%64==0, N%64==0, K%32==0, ptrs 16B aligned.
__global__ __launch_bounds__(256) void k_gemm(const bf16* __restrict__ A,
                                              const float* __restrict__ B,
                                              bf16* __restrict__ C,
                                              int M, int N, int K) {
    __shared__ float As[32][64];  // [k][m]
    __shared__ float Bs[32][64];  // [k][n]
    int t = threadIdx.x;
    int tx = t & 15, ty = t >> 4;
    int bm = blockIdx.x * 64;
    int bn = blockIdx.y * 64;
    float acc[4][4] = {};
    for (int kb = 0; kb < K; kb += 32) {
        {   // A tile: 64 rows x 32 k, 8 contiguous (along K) bf16 per thread
            int l = t * 8;
            int m = l >> 5, k = l & 31;
            uint4 p = *reinterpret_cast<const uint4*>(A + (size_t)(bm + m) * K + kb + k);
            float f[8]; unpack8(p, f);
#pragma unroll
            for (int i = 0; i < 8; i++) As[k + i][m] = f[i];
        }
        {   // B tile: 32 k x 64 n, 8 contiguous (along N) f32 per thread
            int l = t * 8;
            int k = l >> 6, n = l & 63;
            const float* src = B + (size_t)(kb + k) * N + bn + n;
            float4 p0 = *reinterpret_cast<const float4*>(src);
            float4 p1 = *reinterpret_cast<const float4*>(src + 4);
            *reinterpret_cast<float4*>(&Bs[k][n]) = p0;
            *reinterpret_cast<float4*>(&Bs[k][n + 4]) = p1;
        }
        __syncthreads();
#pragma unroll
        for (int k = 0; k < 32; k++) {
            float4 av = *reinterpret_cast<const float4*>(&As[k][ty * 4]);
            float4 bv = *reinterpret_cast<const float4*>(&Bs[k][tx * 4]);
            float a[4] = {av.x, av.y, av.z, av.w};
            float b[4] = {bv.x, bv.y, bv.z, bv.w};
#pragma unroll
            for (int i = 0; i < 4; i++)
#pragma unroll
                for (int j = 0; j < 4; j++) acc[i][j] += a[i] * b[j];
        }
        __syncthreads();
    }
#pragma unroll
    for (int i = 0; i < 4; i++) {
        size_t m = bm + ty * 4 + i;
#pragma unroll
        for (int j = 0; j < 4; j++)
            C[m * N + bn + tx * 4 + j] = __float2bfloat16(acc[i][j]);
    }
}

// ---------- edge scatter-add: agg[col] += xw[row] * dinv[row]*dinv[col] ----------
template <int F>
__global__ __launch_bounds__(256) void k_agg(const int* __restrict__ row,
                                             const int* __restrict__ col,
                                             const float* __restrict__ dinv,
                                             const bf16* __restrict__ xw,
                                             float* __restrict__ agg, int E) {
    constexpr int TPE = F / 4;
    int tid = blockIdx.x * 256 + threadIdx.x;
    int e = tid / TPE;
    if (e >= E) return;
    int fi = (tid % TPE) * 4;
    int r = row[e], c = col[e];
    float nrm = dinv[r] * dinv[c];
    ushort4 p = *reinterpret_cast<const ushort4*>(xw + (size_t)r * F + fi);
    float* dst = agg + (size_t)c * F + fi;
    atomicAdd(dst + 0, b2f_us(p.x) * nrm);
    atomicAdd(dst + 1, b2f_us(p.y) * nrm);
    atomicAdd(dst + 2, b2f_us(p.z) * nrm);
    atomicAdd(dst + 3, b2f_us(p.w) * nrm);
}

// ---------- finalize: h = relu(agg + xw*dinv^2 + b), bf16 out ----------
__global__ __launch_bounds__(256) void k_finalize(const float* __restrict__ agg,
                                                  const bf16* __restrict__ xw,
                                                  const float* __restrict__ dinv,
                                                  const float* __restrict__ bias,
                                                  bf16* __restrict__ h,
                                                  int total4, int F) {
    int idx = blockIdx.x * 256 + threadIdx.x;  // over N*F/4
    if (idx >= total4) return;
    int tpf = F >> 2;
    int n = idx / tpf;
    int f4 = (idx - n * tpf) * 4;
    float d2 = dinv[n] * dinv[n];
    size_t base = (size_t)n * F + f4;
    float4 a = *reinterpret_cast<const float4*>(agg + base);
    ushort4 xp = *reinterpret_cast<const ushort4*>(xw + base);
    float4 bp = *reinterpret_cast<const float4*>(bias + f4);
    float v0 = fmaxf(a.x + b2f_us(xp.x) * d2 + bp.x, 0.f);
    float v1 = fmaxf(a.y + b2f_us(xp.y) * d2 + bp.y, 0.f);
    float v2 = fmaxf(a.z + b2f_us(xp.z) * d2 + bp.z, 0.f);
    float v3 = fmaxf(a.w + b2f_us(xp.w) * d2 + bp.w, 0.f);
    ushort4 r;
    r.x = f2b_us(v0); r.y = f2b_us(v1); r.z = f2b_us(v2); r.w = f2b_us(v3);
    *reinterpret_cast<ushort4*>(h + base) = r;
}

// ---------- pooling (fuses layer-3 finalize): mean & max over 1024 nodes/graph ----------
__global__ __launch_bounds__(256) void k_pool(const float* __restrict__ agg,
                                              const bf16* __restrict__ xw,
                                              const float* __restrict__ dinv,
                                              const float* __restrict__ b3,
                                              float* __restrict__ pooled) {
    int g = blockIdx.x;
    int f = blockIdx.y * 256 + threadIdx.x;  // < 512
    float bias = b3[f];
    float sum = 0.f, mx = 0.f;  // relu output >= 0
    int n0 = g * 1024;
    for (int n = n0; n < n0 + 1024; ++n) {
        size_t idx = (size_t)n * 512 + f;
        float d = dinv[n];
        float v = agg[idx] + __bfloat162float(xw[idx]) * d * d + bias;
        v = fmaxf(v, 0.f);
        sum += v;
        mx = fmaxf(mx, v);
    }
    pooled[g * 1024 + f] = sum * (1.0f / 1024.0f);
    pooled[g * 1024 + 512 + f] = mx;
}

// ---------- MLP head ----------
__global__ __launch_bounds__(512) void k_mlp1(const float* __restrict__ pooled,
                                              const float* __restrict__ Wm1,
                                              const float* __restrict__ bm1,
                                              float* __restrict__ o) {
    int g = blockIdx.x;
    int f = threadIdx.x;  // 512
    __shared__ float hg[1024];
    hg[f] = pooled[g * 1024 + f];
    hg[f + 512] = pooled[g * 1024 + 512 + f];
    __syncthreads();
    float acc = bm1[f];
#pragma unroll 4
    for (int k = 0; k < 1024; ++k)
        acc += hg[k] * Wm1[k * 512 + f];
    o[g * 512 + f] = fmaxf(acc, 0.f);
}

__global__ __launch_bounds__(64) void k_mlp2(const float* __restrict__ h,
                                             const float* __restrict__ Wm2,
                                             const float* __restrict__ bm2,
                                             float* __restrict__ out) {
    int g = blockIdx.x;
    int j = threadIdx.x;
    if (j < 10) {
        float acc = bm2[j];
        for (int k = 0; k < 512; ++k)
            acc += h[g * 512 + k] * Wm2[k * 10 + j];
        out[g * 10 + j] = acc;
    }
}

extern "C" void kernel_launch(void* const* d_in, const int* in_sizes, int n_in,
                              void* d_out, int out_size, void* d_ws, size_t ws_size,
                              hipStream_t stream) {
    const float* x   = (const float*)d_in[0];
    const int*   ei  = (const int*)d_in[1];
    const float* W1  = (const float*)d_in[3];
    const float* b1  = (const float*)d_in[4];
    const float* W2  = (const float*)d_in[5];
    const float* b2  = (const float*)d_in[6];
    const float* W3  = (const float*)d_in[7];
    const float* b3  = (const float*)d_in[8];
    const float* Wm1 = (const float*)d_in[9];
    const float* bm1 = (const float*)d_in[10];
    const float* Wm2 = (const float*)d_in[11];
    const float* bm2 = (const float*)d_in[12];
    float* out = (float*)d_out;

    const int N = in_sizes[0] / 3;  // 65536
    const int E = in_sizes[1] / 2;  // 524288
    const int* row = ei;
    const int* col = ei + E;

    char* ws = (char*)d_ws;
    size_t off = 0;
    auto alloc = [&](size_t bytes) {
        void* p = ws + off;
        off += (bytes + 255) & ~(size_t)255;
        return p;
    };
    float* dinv   = (float*)alloc((size_t)N * 4);
    float* agg    = (float*)alloc((size_t)N * 512 * 4);
    bf16*  xw     = (bf16*)alloc((size_t)N * 512 * 2);
    bf16*  h1     = (bf16*)alloc((size_t)N * 64 * 2);
    bf16*  h2     = (bf16*)alloc((size_t)N * 256 * 2);
    float* pooled = (float*)alloc(64 * 1024 * 4);
    float* m1     = (float*)alloc(64 * 512 * 4);

    // degree -> dinv
    hipMemsetAsync(dinv, 0, (size_t)N * 4, stream);
    k_count<<<(E + 255) / 256, 256, 0, stream>>>(col, dinv, E);
    k_rsqrt<<<(N + 255) / 256, 256, 0, stream>>>(dinv, N);

    // ---- layer 1: 3 -> 64 ----
    k_gemm1<<<(N * 64) / 256, 256, 0, stream>>>(x, W1, xw, N);
    hipMemsetAsync(agg, 0, (size_t)N * 64 * 4, stream);
    k_agg<64><<<(E * 16 + 255) / 256, 256, 0, stream>>>(row, col, dinv, xw, agg, E);
    k_finalize<<<(N * 64 / 4 + 255) / 256, 256, 0, stream>>>(agg, xw, dinv, b1, h1, N * 64 / 4, 64);

    // ---- layer 2: 64 -> 256 ----
    k_gemm<<<dim3(N / 64, 256 / 64), 256, 0, stream>>>(h1, W2, xw, N, 256, 64);
    hipMemsetAsync(agg, 0, (size_t)N * 256 * 4, stream);
    k_agg<256><<<(E * 64 + 255) / 256, 256, 0, stream>>>(row, col, dinv, xw, agg, E);
    k_finalize<<<(N * 256 / 4 + 255) / 256, 256, 0, stream>>>(agg, xw, dinv, b2, h2, N * 256 / 4, 256);

    // ---- layer 3: 256 -> 512 (finalize fused into pooling) ----
    k_gemm<<<dim3(N / 64, 512 / 64), 256, 0, stream>>>(h2, W3, xw, N, 512, 256);
    hipMemsetAsync(agg, 0, (size_t)N * 512 * 4, stream);
    k_agg<512><<<(E * 128 + 255) / 256, 256, 0, stream>>>(row, col, dinv, xw, agg, E);

    // ---- pool + MLP head ----
    k_pool<<<dim3(64, 2), 256, 0, stream>>>(agg, xw, dinv, b3, pooled);
    k_mlp1<<<64, 512, 0, stream>>>(pooled, Wm1, bm1, m1);
    k_mlp2<<<64, 64, 0, stream>>>(m1, Wm2, bm2, out);
}

// Round 4
// 832.248 us; speedup vs baseline: 7.5171x; 7.5171x over previous
//
#include <hip/hip_runtime.h>
#include <hip/hip_bf16.h>

typedef __hip_bfloat16 bf16;

// ---------- helpers ----------
__device__ __forceinline__ float b2f_us(unsigned short u) {
    union { unsigned int i; float f; } c;
    c.i = ((unsigned int)u) << 16;
    return c.f;
}
__device__ __forceinline__ unsigned short f2b_us(float f) {
    bf16 h = __float2bfloat16(f);
    return *reinterpret_cast<unsigned short*>(&h);
}
__device__ __forceinline__ void unpack8(uint4 p, float* f) {
    f[0] = b2f_us(p.x & 0xffff); f[1] = b2f_us(p.x >> 16);
    f[2] = b2f_us(p.y & 0xffff); f[3] = b2f_us(p.y >> 16);
    f[4] = b2f_us(p.z & 0xffff); f[5] = b2f_us(p.z >> 16);
    f[6] = b2f_us(p.w & 0xffff); f[7] = b2f_us(p.w >> 16);
}

// ---------- CSR build ----------
__global__ __launch_bounds__(256) void k_count(const int* __restrict__ col,
                                               int* __restrict__ cnt, int E) {
    int e = blockIdx.x * 256 + threadIdx.x;
    if (e < E) atomicAdd(cnt + col[e], 1);
}
__global__ __launch_bounds__(256) void k_rsqrt(const int* __restrict__ cnt,
                                               float* __restrict__ dinv, int N) {
    int i = blockIdx.x * 256 + threadIdx.x;
    if (i < N) dinv[i] = rsqrtf((float)cnt[i] + 1.0f);  // +1 self-loop
}
// single-block exclusive prefix sum over N (N % 1024 == 0)
__global__ __launch_bounds__(1024) void k_scan(const int* __restrict__ cnt,
                                               int* __restrict__ rowptr, int N) {
    __shared__ int part[1024];
    int t = threadIdx.x;
    int per = N / 1024;
    int base = t * per;
    int s = 0;
    for (int i = 0; i < per; i++) s += cnt[base + i];
    part[t] = s;
    __syncthreads();
    for (int off = 1; off < 1024; off <<= 1) {
        int v = (t >= off) ? part[t - off] : 0;
        __syncthreads();
        part[t] += v;
        __syncthreads();
    }
    int excl = (t == 0) ? 0 : part[t - 1];
    for (int i = 0; i < per; i++) {
        rowptr[base + i] = excl;
        excl += cnt[base + i];
    }
}
__global__ __launch_bounds__(256) void k_scatter(const int* __restrict__ row,
                                                 const int* __restrict__ col,
                                                 const float* __restrict__ dinv,
                                                 const int* __restrict__ rowptr,
                                                 int* __restrict__ fill,
                                                 int2* __restrict__ adj, int E) {
    int e = blockIdx.x * 256 + threadIdx.x;
    if (e >= E) return;
    int r = row[e], c = col[e];
    int pos = rowptr[c] + atomicAdd(fill + c, 1);
    adj[pos] = make_int2(r, __float_as_int(dinv[r]));
}

// ---------- layer-1 GEMM: [N,3] @ [3,64], f32 in, bf16 out ----------
__global__ __launch_bounds__(256) void k_gemm1(const float* __restrict__ x,
                                               const float* __restrict__ W,
                                               bf16* __restrict__ xw, int M) {
    __shared__ float w[192];
    int t = threadIdx.x;
    if (t < 192) w[t] = W[t];
    __syncthreads();
    int idx = blockIdx.x * 256 + t;
    if (idx < M * 64) {
        int n = idx >> 6, f = idx & 63;
        float acc = x[n * 3] * w[f] + x[n * 3 + 1] * w[64 + f] + x[n * 3 + 2] * w[128 + f];
        xw[idx] = __float2bfloat16(acc);
    }
}

// ---------- tiled GEMM: A[M,K](bf16) @ B[K,N](f32) -> C[M,N](bf16), f32 acc ----------
__global__ __launch_bounds__(256) void k_gemm(const bf16* __restrict__ A,
                                              const float* __restrict__ B,
                                              bf16* __restrict__ C,
                                              int M, int N, int K) {
    __shared__ float As[32][64];
    __shared__ float Bs[32][64];
    int t = threadIdx.x;
    int tx = t & 15, ty = t >> 4;
    int bm = blockIdx.x * 64;
    int bn = blockIdx.y * 64;
    float acc[4][4] = {};
    for (int kb = 0; kb < K; kb += 32) {
        {
            int l = t * 8;
            int m = l >> 5, k = l & 31;
            uint4 p = *reinterpret_cast<const uint4*>(A + (size_t)(bm + m) * K + kb + k);
            float f[8]; unpack8(p, f);
#pragma unroll
            for (int i = 0; i < 8; i++) As[k + i][m] = f[i];
        }
        {
            int l = t * 8;
            int k = l >> 6, n = l & 63;
            const float* src = B + (size_t)(kb + k) * N + bn + n;
            *reinterpret_cast<float4*>(&Bs[k][n]) = *reinterpret_cast<const float4*>(src);
            *reinterpret_cast<float4*>(&Bs[k][n + 4]) = *reinterpret_cast<const float4*>(src + 4);
        }
        __syncthreads();
#pragma unroll
        for (int k = 0; k < 32; k++) {
            float4 av = *reinterpret_cast<const float4*>(&As[k][ty * 4]);
            float4 bv = *reinterpret_cast<const float4*>(&Bs[k][tx * 4]);
            float a[4] = {av.x, av.y, av.z, av.w};
            float b[4] = {bv.x, bv.y, bv.z, bv.w};
#pragma unroll
            for (int i = 0; i < 4; i++)
#pragma unroll
                for (int j = 0; j < 4; j++) acc[i][j] += a[i] * b[j];
        }
        __syncthreads();
    }
#pragma unroll
    for (int i = 0; i < 4; i++) {
        size_t m = bm + ty * 4 + i;
#pragma unroll
        for (int j = 0; j < 4; j++)
            C[m * N + bn + tx * 4 + j] = __float2bfloat16(acc[i][j]);
    }
}

// ---------- CSR gather aggregation, fused finalize: h = relu(sum + self + b) ----------
// One thread per (node, 4-feature chunk). Lanes covering one node are contiguous,
// so adjacency reads broadcast and xw reads coalesce.
template <int F>
__global__ __launch_bounds__(256) void k_gather(const int2* __restrict__ adj,
                                                const int* __restrict__ rowptr,
                                                const int* __restrict__ cnt,
                                                const float* __restrict__ dinv,
                                                const bf16* __restrict__ xw,
                                                const float* __restrict__ bias,
                                                bf16* __restrict__ h, int N) {
    constexpr int LPN = F / 4;           // lanes per node
    constexpr int NPB = 256 / LPN;       // nodes per block
    int t = threadIdx.x;
    int node = blockIdx.x * NPB + t / LPN;
    if (node >= N) return;               // guard against grid overshoot
    int fbase = (t % LPN) * 4;
    float d = dinv[node];
    size_t sbase = (size_t)node * F + fbase;
    ushort4 sp = *reinterpret_cast<const ushort4*>(xw + sbase);
    float4 bv = *reinterpret_cast<const float4*>(bias + fbase);
    float d2 = d * d;
    float a0 = b2f_us(sp.x) * d2 + bv.x;
    float a1 = b2f_us(sp.y) * d2 + bv.y;
    float a2 = b2f_us(sp.z) * d2 + bv.z;
    float a3 = b2f_us(sp.w) * d2 + bv.w;
    int beg = rowptr[node];
    int end = beg + cnt[node];
    for (int e = beg; e < end; ++e) {
        int2 ad = adj[e];
        float w = __int_as_float(ad.y) * d;
        ushort4 p = *reinterpret_cast<const ushort4*>(xw + (size_t)ad.x * F + fbase);
        a0 += b2f_us(p.x) * w;
        a1 += b2f_us(p.y) * w;
        a2 += b2f_us(p.z) * w;
        a3 += b2f_us(p.w) * w;
    }
    ushort4 r;
    r.x = f2b_us(fmaxf(a0, 0.f));
    r.y = f2b_us(fmaxf(a1, 0.f));
    r.z = f2b_us(fmaxf(a2, 0.f));
    r.w = f2b_us(fmaxf(a3, 0.f));
    *reinterpret_cast<ushort4*>(h + sbase) = r;
}

// ---------- pooling: mean & max over 1024 nodes/graph of finalized h3 ----------
__global__ __launch_bounds__(256) void k_pool(const bf16* __restrict__ h3,
                                              float* __restrict__ pooled) {
    int g = blockIdx.x;
    int f = blockIdx.y * 256 + threadIdx.x;  // < 512
    float sum = 0.f, mx = 0.f;               // relu output >= 0
    int n0 = g * 1024;
    for (int n = n0; n < n0 + 1024; ++n) {
        float v = b2f_us(*reinterpret_cast<const unsigned short*>(h3 + (size_t)n * 512 + f));
        sum += v;
        mx = fmaxf(mx, v);
    }
    pooled[g * 1024 + f] = sum * (1.0f / 1024.0f);
    pooled[g * 1024 + 512 + f] = mx;
}

// ---------- MLP head ----------
__global__ __launch_bounds__(512) void k_mlp1(const float* __restrict__ pooled,
                                              const float* __restrict__ Wm1,
                                              const float* __restrict__ bm1,
                                              float* __restrict__ o) {
    int g = blockIdx.x;
    int f = threadIdx.x;
    __shared__ float hg[1024];
    hg[f] = pooled[g * 1024 + f];
    hg[f + 512] = pooled[g * 1024 + 512 + f];
    __syncthreads();
    float acc = bm1[f];
#pragma unroll 4
    for (int k = 0; k < 1024; ++k)
        acc += hg[k] * Wm1[k * 512 + f];
    o[g * 512 + f] = fmaxf(acc, 0.f);
}

__global__ __launch_bounds__(64) void k_mlp2(const float* __restrict__ h,
                                             const float* __restrict__ Wm2,
                                             const float* __restrict__ bm2,
                                             float* __restrict__ out) {
    int g = blockIdx.x;
    int j = threadIdx.x;
    if (j < 10) {
        float acc = bm2[j];
        for (int k = 0; k < 512; ++k)
            acc += h[g * 512 + k] * Wm2[k * 10 + j];
        out[g * 10 + j] = acc;
    }
}

extern "C" void kernel_launch(void* const* d_in, const int* in_sizes, int n_in,
                              void* d_out, int out_size, void* d_ws, size_t ws_size,
                              hipStream_t stream) {
    const float* x   = (const float*)d_in[0];
    const int*   ei  = (const int*)d_in[1];
    const float* W1  = (const float*)d_in[3];
    const float* b1  = (const float*)d_in[4];
    const float* W2  = (const float*)d_in[5];
    const float* b2  = (const float*)d_in[6];
    const float* W3  = (const float*)d_in[7];
    const float* b3  = (const float*)d_in[8];
    const float* Wm1 = (const float*)d_in[9];
    const float* bm1 = (const float*)d_in[10];
    const float* Wm2 = (const float*)d_in[11];
    const float* bm2 = (const float*)d_in[12];
    float* out = (float*)d_out;

    const int N = in_sizes[0] / 3;  // 65536
    const int E = in_sizes[1] / 2;  // 524288
    const int* row = ei;
    const int* col = ei + E;

    char* ws = (char*)d_ws;
    size_t off = 0;
    auto alloc = [&](size_t bytes) {
        void* p = ws + off;
        off += (bytes + 255) & ~(size_t)255;
        return p;
    };
    int*   cnt    = (int*)alloc((size_t)N * 4);
    int*   rowptr = (int*)alloc((size_t)N * 4);
    int*   fill   = (int*)alloc((size_t)N * 4);
    float* dinv   = (float*)alloc((size_t)N * 4);
    int2*  adj    = (int2*)alloc((size_t)E * 8);
    bf16*  xw     = (bf16*)alloc((size_t)N * 512 * 2);
    bf16*  h1     = (bf16*)alloc((size_t)N * 64 * 2);
    bf16*  h2     = (bf16*)alloc((size_t)N * 256 * 2);
    bf16*  h3     = (bf16*)alloc((size_t)N * 512 * 2);
    float* pooled = (float*)alloc(64 * 1024 * 4);
    float* m1     = (float*)alloc(64 * 512 * 4);

    // ---- CSR build (once; reused by all 3 layers) ----
    hipMemsetAsync(cnt, 0, (size_t)N * 4, stream);
    hipMemsetAsync(fill, 0, (size_t)N * 4, stream);
    k_count<<<(E + 255) / 256, 256, 0, stream>>>(col, cnt, E);
    k_rsqrt<<<(N + 255) / 256, 256, 0, stream>>>(cnt, dinv, N);
    k_scan<<<1, 1024, 0, stream>>>(cnt, rowptr, N);
    k_scatter<<<(E + 255) / 256, 256, 0, stream>>>(row, col, dinv, rowptr, fill, adj, E);

    // ---- layer 1: 3 -> 64 ----  (threads = N*16)
    k_gemm1<<<(N * 64) / 256, 256, 0, stream>>>(x, W1, xw, N);
    k_gather<64><<<(N * 16) / 256, 256, 0, stream>>>(adj, rowptr, cnt, dinv, xw, b1, h1, N);

    // ---- layer 2: 64 -> 256 ----  (threads = N*64)
    k_gemm<<<dim3(N / 64, 256 / 64), 256, 0, stream>>>(h1, W2, xw, N, 256, 64);
    k_gather<256><<<(N * 64) / 256, 256, 0, stream>>>(adj, rowptr, cnt, dinv, xw, b2, h2, N);

    // ---- layer 3: 256 -> 512 ----  (threads = N*128)
    k_gemm<<<dim3(N / 64, 512 / 64), 256, 0, stream>>>(h2, W3, xw, N, 512, 256);
    k_gather<512><<<(N * 128) / 256, 256, 0, stream>>>(adj, rowptr, cnt, dinv, xw, b3, h3, N);

    // ---- pool + MLP head ----
    k_pool<<<dim3(64, 2), 256, 0, stream>>>(h3, pooled);
    k_mlp1<<<64, 512, 0, stream>>>(pooled, Wm1, bm1, m1);
    k_mlp2<<<64, 64, 0, stream>>>(m1, Wm2, bm2, out);
}

// Round 5
// 689.539 us; speedup vs baseline: 9.0729x; 1.2070x over previous
//
#include <hip/hip_runtime.h>
#include <hip/hip_bf16.h>

typedef __hip_bfloat16 bf16;
typedef short bf16x8 __attribute__((ext_vector_type(8)));
typedef float f32x4 __attribute__((ext_vector_type(4)));

// ---------- helpers ----------
__device__ __forceinline__ float b2f_us(unsigned short u) {
    union { unsigned int i; float f; } c;
    c.i = ((unsigned int)u) << 16;
    return c.f;
}
__device__ __forceinline__ unsigned short f2b_us(float f) {
    bf16 h = __float2bfloat16(f);
    return *reinterpret_cast<unsigned short*>(&h);
}

// async 16B global -> LDS (global_load_lds_dwordx4)
__device__ __forceinline__ void async_copy16(const bf16* g, bf16* l) {
    __builtin_amdgcn_global_load_lds(
        (const __attribute__((address_space(1))) unsigned int*)g,
        (__attribute__((address_space(3))) unsigned int*)l, 16, 0, 0);
}

// ---------- CSR build ----------
__global__ __launch_bounds__(256) void k_count(const int* __restrict__ col,
                                               int* __restrict__ cnt, int E) {
    int e = blockIdx.x * 256 + threadIdx.x;
    if (e < E) atomicAdd(cnt + col[e], 1);
}
__global__ __launch_bounds__(256) void k_rsqrt(const int* __restrict__ cnt,
                                               float* __restrict__ dinv, int N) {
    int i = blockIdx.x * 256 + threadIdx.x;
    if (i < N) dinv[i] = rsqrtf((float)cnt[i] + 1.0f);  // +1 self-loop
}
__global__ __launch_bounds__(1024) void k_scan(const int* __restrict__ cnt,
                                               int* __restrict__ rowptr, int N) {
    __shared__ int part[1024];
    int t = threadIdx.x;
    int per = N / 1024;
    int base = t * per;
    int s = 0;
    for (int i = 0; i < per; i++) s += cnt[base + i];
    part[t] = s;
    __syncthreads();
    for (int off = 1; off < 1024; off <<= 1) {
        int v = (t >= off) ? part[t - off] : 0;
        __syncthreads();
        part[t] += v;
        __syncthreads();
    }
    int excl = (t == 0) ? 0 : part[t - 1];
    for (int i = 0; i < per; i++) {
        rowptr[base + i] = excl;
        excl += cnt[base + i];
    }
}
__global__ __launch_bounds__(256) void k_scatter(const int* __restrict__ row,
                                                 const int* __restrict__ col,
                                                 const float* __restrict__ dinv,
                                                 const int* __restrict__ rowptr,
                                                 int* __restrict__ fill,
                                                 int2* __restrict__ adj, int E) {
    int e = blockIdx.x * 256 + threadIdx.x;
    if (e >= E) return;
    int r = row[e], c = col[e];
    int pos = rowptr[c] + atomicAdd(fill + c, 1);
    adj[pos] = make_int2(r, __float_as_int(dinv[r]));
}

// ---------- weight prep: W[K,N] f32 -> WT[N,K] bf16 ----------
__global__ __launch_bounds__(256) void k_prep(const float* __restrict__ W,
                                              bf16* __restrict__ WT, int K, int N) {
    int idx = blockIdx.x * 256 + threadIdx.x;
    if (idx >= K * N) return;
    int k = idx / N, n = idx - k * N;
    WT[(size_t)n * K + k] = __float2bfloat16(W[idx]);
}

// ---------- layer-1 GEMM: [N,3] @ [3,64], f32 in, bf16 out ----------
__global__ __launch_bounds__(256) void k_gemm1(const float* __restrict__ x,
                                               const float* __restrict__ W,
                                               bf16* __restrict__ xw, int M) {
    __shared__ float w[192];
    int t = threadIdx.x;
    if (t < 192) w[t] = W[t];
    __syncthreads();
    int idx = blockIdx.x * 256 + t;
    if (idx < M * 64) {
        int n = idx >> 6, f = idx & 63;
        float acc = x[n * 3] * w[f] + x[n * 3 + 1] * w[64 + f] + x[n * 3 + 2] * w[128 + f];
        xw[idx] = __float2bfloat16(acc);
    }
}

// ---------- MFMA GEMM: A[M,K](bf16,row) @ BT[N,K](bf16,row)^T -> C[M,N](bf16)
// 128x128 tile, BK=32, 256 thr = 4 waves (2x2 of 64x64), m97-style staging.
// Requires M%128==0, N%128==0, K%32==0.
__global__ __launch_bounds__(256) void k_gemm_mfma(const bf16* __restrict__ A,
                                                   const bf16* __restrict__ BT,
                                                   bf16* __restrict__ C,
                                                   int M, int N, int K) {
    __shared__ bf16 As[128 * 32];  // [m][k]
    __shared__ bf16 Bs[128 * 32];  // [n][k]
    const int t = threadIdx.x;
    const int wave = t >> 6, lane = t & 63;
    const int quad = lane >> 4, l16 = lane & 15;
    const int wm = wave & 1, wn = wave >> 1;
    const int m0 = blockIdx.x * 128;
    const int n0 = blockIdx.y * 128;

    f32x4 acc[4][4] = {};

    for (int kb = 0; kb < K; kb += 32) {
        // stage A and B^T tiles: 512 chunks of 16B each; per wave 2 rounds x 64 lanes
#pragma unroll
        for (int rnd = 0; rnd < 2; ++rnd) {
            int c = (rnd * 4 + wave) * 64 + lane;  // 0..511
            int r = c >> 2, seg = c & 3;
            async_copy16(A + (size_t)(m0 + r) * K + kb + seg * 8, As + c * 8);
            async_copy16(BT + (size_t)(n0 + r) * K + kb + seg * 8, Bs + c * 8);
        }
        __syncthreads();  // drains vmcnt (global_load_lds) before use

        bf16x8 af[4], bfr[4];
#pragma unroll
        for (int i = 0; i < 4; i++)
            af[i] = *reinterpret_cast<const bf16x8*>(&As[(wm * 64 + i * 16 + l16) * 32 + quad * 8]);
#pragma unroll
        for (int j = 0; j < 4; j++)
            bfr[j] = *reinterpret_cast<const bf16x8*>(&Bs[(wn * 64 + j * 16 + l16) * 32 + quad * 8]);
#pragma unroll
        for (int i = 0; i < 4; i++)
#pragma unroll
            for (int j = 0; j < 4; j++)
                acc[i][j] = __builtin_amdgcn_mfma_f32_16x16x32_bf16(af[i], bfr[j], acc[i][j], 0, 0, 0);
        __syncthreads();  // protect LDS before next stage
    }

#pragma unroll
    for (int i = 0; i < 4; i++) {
        int row = m0 + wm * 64 + i * 16 + quad * 4;
#pragma unroll
        for (int j = 0; j < 4; j++) {
            int cn = n0 + wn * 64 + j * 16 + l16;
#pragma unroll
            for (int r = 0; r < 4; r++)
                C[(size_t)(row + r) * N + cn] = __float2bfloat16(acc[i][j][r]);
        }
    }
}

// ---------- CSR gather aggregation, fused finalize: h = relu(sum + self + b) ----------
template <int F>
__global__ __launch_bounds__(256) void k_gather(const int2* __restrict__ adj,
                                                const int* __restrict__ rowptr,
                                                const int* __restrict__ cnt,
                                                const float* __restrict__ dinv,
                                                const bf16* __restrict__ xw,
                                                const float* __restrict__ bias,
                                                bf16* __restrict__ h, int N) {
    constexpr int LPN = F / 4;           // lanes per node
    constexpr int NPB = 256 / LPN;       // nodes per block
    int t = threadIdx.x;
    int node = blockIdx.x * NPB + t / LPN;
    if (node >= N) return;
    int fbase = (t % LPN) * 4;
    float d = dinv[node];
    size_t sbase = (size_t)node * F + fbase;
    ushort4 sp = *reinterpret_cast<const ushort4*>(xw + sbase);
    float4 bv = *reinterpret_cast<const float4*>(bias + fbase);
    float d2 = d * d;
    float a0 = b2f_us(sp.x) * d2 + bv.x;
    float a1 = b2f_us(sp.y) * d2 + bv.y;
    float a2 = b2f_us(sp.z) * d2 + bv.z;
    float a3 = b2f_us(sp.w) * d2 + bv.w;
    int beg = rowptr[node];
    int end = beg + cnt[node];
    for (int e = beg; e < end; ++e) {
        int2 ad = adj[e];
        float w = __int_as_float(ad.y) * d;
        ushort4 p = *reinterpret_cast<const ushort4*>(xw + (size_t)ad.x * F + fbase);
        a0 += b2f_us(p.x) * w;
        a1 += b2f_us(p.y) * w;
        a2 += b2f_us(p.z) * w;
        a3 += b2f_us(p.w) * w;
    }
    ushort4 r;
    r.x = f2b_us(fmaxf(a0, 0.f));
    r.y = f2b_us(fmaxf(a1, 0.f));
    r.z = f2b_us(fmaxf(a2, 0.f));
    r.w = f2b_us(fmaxf(a3, 0.f));
    *reinterpret_cast<ushort4*>(h + sbase) = r;
}

// ---------- pooling ----------
__global__ __launch_bounds__(256) void k_pool(const bf16* __restrict__ h3,
                                              float* __restrict__ pooled) {
    int g = blockIdx.x;
    int f = blockIdx.y * 256 + threadIdx.x;  // < 512
    float sum = 0.f, mx = 0.f;
    int n0 = g * 1024;
    for (int n = n0; n < n0 + 1024; ++n) {
        float v = b2f_us(*reinterpret_cast<const unsigned short*>(h3 + (size_t)n * 512 + f));
        sum += v;
        mx = fmaxf(mx, v);
    }
    pooled[g * 1024 + f] = sum * (1.0f / 1024.0f);
    pooled[g * 1024 + 512 + f] = mx;
}

// ---------- MLP head ----------
__global__ __launch_bounds__(512) void k_mlp1(const float* __restrict__ pooled,
                                              const float* __restrict__ Wm1,
                                              const float* __restrict__ bm1,
                                              float* __restrict__ o) {
    int g = blockIdx.x;
    int f = threadIdx.x;
    __shared__ float hg[1024];
    hg[f] = pooled[g * 1024 + f];
    hg[f + 512] = pooled[g * 1024 + 512 + f];
    __syncthreads();
    float acc = bm1[f];
#pragma unroll 4
    for (int k = 0; k < 1024; ++k)
        acc += hg[k] * Wm1[k * 512 + f];
    o[g * 512 + f] = fmaxf(acc, 0.f);
}

__global__ __launch_bounds__(64) void k_mlp2(const float* __restrict__ h,
                                             const float* __restrict__ Wm2,
                                             const float* __restrict__ bm2,
                                             float* __restrict__ out) {
    int g = blockIdx.x;
    int j = threadIdx.x;
    if (j < 10) {
        float acc = bm2[j];
        for (int k = 0; k < 512; ++k)
            acc += h[g * 512 + k] * Wm2[k * 10 + j];
        out[g * 10 + j] = acc;
    }
}

extern "C" void kernel_launch(void* const* d_in, const int* in_sizes, int n_in,
                              void* d_out, int out_size, void* d_ws, size_t ws_size,
                              hipStream_t stream) {
    const float* x   = (const float*)d_in[0];
    const int*   ei  = (const int*)d_in[1];
    const float* W1  = (const float*)d_in[3];
    const float* b1  = (const float*)d_in[4];
    const float* W2  = (const float*)d_in[5];
    const float* b2  = (const float*)d_in[6];
    const float* W3  = (const float*)d_in[7];
    const float* b3  = (const float*)d_in[8];
    const float* Wm1 = (const float*)d_in[9];
    const float* bm1 = (const float*)d_in[10];
    const float* Wm2 = (const float*)d_in[11];
    const float* bm2 = (const float*)d_in[12];
    float* out = (float*)d_out;

    const int N = in_sizes[0] / 3;  // 65536
    const int E = in_sizes[1] / 2;  // 524288
    const int* row = ei;
    const int* col = ei + E;

    char* ws = (char*)d_ws;
    size_t off = 0;
    auto alloc = [&](size_t bytes) {
        void* p = ws + off;
        off += (bytes + 255) & ~(size_t)255;
        return p;
    };
    int*   cnt    = (int*)alloc((size_t)N * 4);
    int*   rowptr = (int*)alloc((size_t)N * 4);
    int*   fill   = (int*)alloc((size_t)N * 4);
    float* dinv   = (float*)alloc((size_t)N * 4);
    int2*  adj    = (int2*)alloc((size_t)E * 8);
    bf16*  xw     = (bf16*)alloc((size_t)N * 512 * 2);
    bf16*  h1     = (bf16*)alloc((size_t)N * 64 * 2);
    bf16*  h2     = (bf16*)alloc((size_t)N * 256 * 2);
    bf16*  h3     = (bf16*)alloc((size_t)N * 512 * 2);
    bf16*  WT2    = (bf16*)alloc(256 * 64 * 2);
    bf16*  WT3    = (bf16*)alloc(512 * 256 * 2);
    float* pooled = (float*)alloc(64 * 1024 * 4);
    float* m1     = (float*)alloc(64 * 512 * 4);

    // ---- CSR build (once; reused by all 3 layers) ----
    hipMemsetAsync(cnt, 0, (size_t)N * 4, stream);
    hipMemsetAsync(fill, 0, (size_t)N * 4, stream);
    k_count<<<(E + 255) / 256, 256, 0, stream>>>(col, cnt, E);
    k_rsqrt<<<(N + 255) / 256, 256, 0, stream>>>(cnt, dinv, N);
    k_scan<<<1, 1024, 0, stream>>>(cnt, rowptr, N);
    k_scatter<<<(E + 255) / 256, 256, 0, stream>>>(row, col, dinv, rowptr, fill, adj, E);

    // ---- weight prep ----
    k_prep<<<(64 * 256 + 255) / 256, 256, 0, stream>>>(W2, WT2, 64, 256);
    k_prep<<<(256 * 512 + 255) / 256, 256, 0, stream>>>(W3, WT3, 256, 512);

    // ---- layer 1: 3 -> 64 ----
    k_gemm1<<<(N * 64) / 256, 256, 0, stream>>>(x, W1, xw, N);
    k_gather<64><<<(N * 16) / 256, 256, 0, stream>>>(adj, rowptr, cnt, dinv, xw, b1, h1, N);

    // ---- layer 2: 64 -> 256 (MFMA) ----
    k_gemm_mfma<<<dim3(N / 128, 256 / 128), 256, 0, stream>>>(h1, WT2, xw, N, 256, 64);
    k_gather<256><<<(N * 64) / 256, 256, 0, stream>>>(adj, rowptr, cnt, dinv, xw, b2, h2, N);

    // ---- layer 3: 256 -> 512 (MFMA) ----
    k_gemm_mfma<<<dim3(N / 128, 512 / 128), 256, 0, stream>>>(h2, WT3, xw, N, 512, 256);
    k_gather<512><<<(N * 128) / 256, 256, 0, stream>>>(adj, rowptr, cnt, dinv, xw, b3, h3, N);

    // ---- pool + MLP head ----
    k_pool<<<dim3(64, 2), 256, 0, stream>>>(h3, pooled);
    k_mlp1<<<64, 512, 0, stream>>>(pooled, Wm1, bm1, m1);
    k_mlp2<<<64, 64, 0, stream>>>(m1, Wm2, bm2, out);
}

// Round 7
// 488.407 us; speedup vs baseline: 12.8092x; 1.4118x over previous
//
#include <hip/hip_runtime.h>
#include <hip/hip_bf16.h>

typedef __hip_bfloat16 bf16;
typedef short bf16x8 __attribute__((ext_vector_type(8)));
typedef float f32x4 __attribute__((ext_vector_type(4)));

// ---------- helpers ----------
__device__ __forceinline__ float b2f_us(unsigned short u) {
    union { unsigned int i; float f; } c;
    c.i = ((unsigned int)u) << 16;
    return c.f;
}
__device__ __forceinline__ unsigned short f2b_us(float f) {
    bf16 h = __float2bfloat16(f);
    return *reinterpret_cast<unsigned short*>(&h);
}

// async 16B global -> LDS (global_load_lds_dwordx4)
__device__ __forceinline__ void async_copy16(const bf16* g, bf16* l) {
    __builtin_amdgcn_global_load_lds(
        (const __attribute__((address_space(1))) unsigned int*)g,
        (__attribute__((address_space(3))) unsigned int*)l, 16, 0, 0);
}

// ---------- CSR build ----------
__global__ __launch_bounds__(256) void k_count(const int* __restrict__ col,
                                               int* __restrict__ cnt, int E) {
    int e = blockIdx.x * 256 + threadIdx.x;
    if (e < E) atomicAdd(cnt + col[e], 1);
}
__global__ __launch_bounds__(256) void k_rsqrt(const int* __restrict__ cnt,
                                               float* __restrict__ dinv, int N) {
    int i = blockIdx.x * 256 + threadIdx.x;
    if (i < N) dinv[i] = rsqrtf((float)cnt[i] + 1.0f);  // +1 self-loop
}
__global__ __launch_bounds__(1024) void k_scan(const int* __restrict__ cnt,
                                               int* __restrict__ rowptr, int N) {
    __shared__ int part[1024];
    int t = threadIdx.x;
    int per = N / 1024;
    int base = t * per;
    int s = 0;
    for (int i = 0; i < per; i++) s += cnt[base + i];
    part[t] = s;
    __syncthreads();
    for (int off = 1; off < 1024; off <<= 1) {
        int v = (t >= off) ? part[t - off] : 0;
        __syncthreads();
        part[t] += v;
        __syncthreads();
    }
    int excl = (t == 0) ? 0 : part[t - 1];
    for (int i = 0; i < per; i++) {
        rowptr[base + i] = excl;
        excl += cnt[base + i];
    }
}
__global__ __launch_bounds__(256) void k_scatter(const int* __restrict__ row,
                                                 const int* __restrict__ col,
                                                 const float* __restrict__ dinv,
                                                 const int* __restrict__ rowptr,
                                                 int* __restrict__ fill,
                                                 int2* __restrict__ adj, int E) {
    int e = blockIdx.x * 256 + threadIdx.x;
    if (e >= E) return;
    int r = row[e], c = col[e];
    int pos = rowptr[c] + atomicAdd(fill + c, 1);
    adj[pos] = make_int2(r, __float_as_int(dinv[r]));
}

// ---------- weight prep: W[K,N] f32 -> WT[N,K] bf16 ----------
__global__ __launch_bounds__(256) void k_prep(const float* __restrict__ W,
                                              bf16* __restrict__ WT, int K, int N) {
    int idx = blockIdx.x * 256 + threadIdx.x;
    if (idx >= K * N) return;
    int k = idx / N, n = idx - k * N;
    WT[(size_t)n * K + k] = __float2bfloat16(W[idx]);
}

// ---------- gather on raw x (F=3, f32): agg1 = Ax (normalized, incl. self) ----------
__global__ __launch_bounds__(256) void k_gather_x(const int2* __restrict__ adj,
                                                  const int* __restrict__ rowptr,
                                                  const int* __restrict__ cnt,
                                                  const float* __restrict__ dinv,
                                                  const float* __restrict__ x,
                                                  float* __restrict__ agg1, int N) {
    int n = blockIdx.x * 256 + threadIdx.x;
    if (n >= N) return;
    float d = dinv[n];
    float d2 = d * d;
    float a0 = x[n * 3] * d2, a1 = x[n * 3 + 1] * d2, a2 = x[n * 3 + 2] * d2;
    int beg = rowptr[n], end = beg + cnt[n];
    for (int e = beg; e < end; ++e) {
        int2 ad = adj[e];
        float w = __int_as_float(ad.y) * d;
        a0 += x[ad.x * 3] * w;
        a1 += x[ad.x * 3 + 1] * w;
        a2 += x[ad.x * 3 + 2] * w;
    }
    agg1[n * 3] = a0; agg1[n * 3 + 1] = a1; agg1[n * 3 + 2] = a2;
}

// ---------- layer-1 GEMM: h1 = relu(agg1[N,3] @ W1[3,64] + b1), bf16 out ----------
__global__ __launch_bounds__(256) void k_gemm1(const float* __restrict__ agg1,
                                               const float* __restrict__ W,
                                               const float* __restrict__ bias,
                                               bf16* __restrict__ h1, int M) {
    __shared__ float w[256];
    int t = threadIdx.x;
    if (t < 192) w[t] = W[t];
    if (t >= 192) w[t] = bias[t - 192];
    __syncthreads();
    int idx = blockIdx.x * 256 + t;
    if (idx < M * 64) {
        int n = idx >> 6, f = idx & 63;
        float acc = agg1[n * 3] * w[f] + agg1[n * 3 + 1] * w[64 + f] +
                    agg1[n * 3 + 2] * w[128 + f] + w[192 + f];
        h1[idx] = __float2bfloat16(fmaxf(acc, 0.f));
    }
}

// ---------- CSR gather (bf16 -> bf16, incl. self term; no bias/relu) ----------
template <int F>
__global__ __launch_bounds__(256) void k_gather_pre(const int2* __restrict__ adj,
                                                    const int* __restrict__ rowptr,
                                                    const int* __restrict__ cnt,
                                                    const float* __restrict__ dinv,
                                                    const bf16* __restrict__ h,
                                                    bf16* __restrict__ agg, int N) {
    constexpr int LPN = F / 4;
    constexpr int NPB = 256 / LPN;
    int t = threadIdx.x;
    int node = blockIdx.x * NPB + t / LPN;
    if (node >= N) return;
    int fbase = (t % LPN) * 4;
    float d = dinv[node];
    size_t sbase = (size_t)node * F + fbase;
    ushort4 sp = *reinterpret_cast<const ushort4*>(h + sbase);
    float d2 = d * d;
    float a0 = b2f_us(sp.x) * d2;
    float a1 = b2f_us(sp.y) * d2;
    float a2 = b2f_us(sp.z) * d2;
    float a3 = b2f_us(sp.w) * d2;
    int beg = rowptr[node];
    int end = beg + cnt[node];
    for (int e = beg; e < end; ++e) {
        int2 ad = adj[e];
        float w = __int_as_float(ad.y) * d;
        ushort4 p = *reinterpret_cast<const ushort4*>(h + (size_t)ad.x * F + fbase);
        a0 += b2f_us(p.x) * w;
        a1 += b2f_us(p.y) * w;
        a2 += b2f_us(p.z) * w;
        a3 += b2f_us(p.w) * w;
    }
    ushort4 r;
    r.x = f2b_us(a0); r.y = f2b_us(a1); r.z = f2b_us(a2); r.w = f2b_us(a3);
    *reinterpret_cast<ushort4*>(agg + sbase) = r;
}

// ---------- MFMA GEMM + bias + relu: C = relu(A @ BT^T + b), bf16 out ----------
// 128x128 tile, BK=32, 256 thr = 4 waves (2x2 of 64x64). M%128==0, N%128==0, K%32==0.
__global__ __launch_bounds__(256) void k_gemm_br(const bf16* __restrict__ A,
                                                 const bf16* __restrict__ BT,
                                                 const float* __restrict__ bias,
                                                 bf16* __restrict__ C,
                                                 int M, int N, int K) {
    __shared__ bf16 As[128 * 32];
    __shared__ bf16 Bs[128 * 32];
    const int t = threadIdx.x;
    const int wave = t >> 6, lane = t & 63;
    const int quad = lane >> 4, l16 = lane & 15;
    const int wm = wave & 1, wn = wave >> 1;
    const int m0 = blockIdx.x * 128;
    const int n0 = blockIdx.y * 128;

    f32x4 acc[4][4] = {};
    for (int kb = 0; kb < K; kb += 32) {
#pragma unroll
        for (int rnd = 0; rnd < 2; ++rnd) {
            int c = (rnd * 4 + wave) * 64 + lane;
            int r = c >> 2, seg = c & 3;
            async_copy16(A + (size_t)(m0 + r) * K + kb + seg * 8, As + c * 8);
            async_copy16(BT + (size_t)(n0 + r) * K + kb + seg * 8, Bs + c * 8);
        }
        __syncthreads();
        bf16x8 af[4], bfr[4];
#pragma unroll
        for (int i = 0; i < 4; i++)
            af[i] = *reinterpret_cast<const bf16x8*>(&As[(wm * 64 + i * 16 + l16) * 32 + quad * 8]);
#pragma unroll
        for (int j = 0; j < 4; j++)
            bfr[j] = *reinterpret_cast<const bf16x8*>(&Bs[(wn * 64 + j * 16 + l16) * 32 + quad * 8]);
#pragma unroll
        for (int i = 0; i < 4; i++)
#pragma unroll
            for (int j = 0; j < 4; j++)
                acc[i][j] = __builtin_amdgcn_mfma_f32_16x16x32_bf16(af[i], bfr[j], acc[i][j], 0, 0, 0);
        __syncthreads();
    }
#pragma unroll
    for (int j = 0; j < 4; j++) {
        int cn = n0 + wn * 64 + j * 16 + l16;
        float bv = bias[cn];
#pragma unroll
        for (int i = 0; i < 4; i++) {
            int row = m0 + wm * 64 + i * 16 + quad * 4;
#pragma unroll
            for (int r = 0; r < 4; r++)
                C[(size_t)(row + r) * N + cn] = __float2bfloat16(fmaxf(acc[i][j][r] + bv, 0.f));
        }
    }
}

// ---------- MFMA GEMM + bias + relu + per-block pool partials (no atomics) ----------
// Each wave writes (sum,max) over its 64 rows for its 64 features to
// partials[((bx*4+by)*2 + wm)*256 + kind*128 + f128], f128 = wn*64+j*16+l16.
__global__ __launch_bounds__(256) void k_gemm_pool(const bf16* __restrict__ A,
                                                   const bf16* __restrict__ BT,
                                                   const float* __restrict__ bias,
                                                   float* __restrict__ partials,
                                                   int M, int N, int K) {
    __shared__ bf16 As[128 * 32];
    __shared__ bf16 Bs[128 * 32];
    const int t = threadIdx.x;
    const int wave = t >> 6, lane = t & 63;
    const int quad = lane >> 4, l16 = lane & 15;
    const int wm = wave & 1, wn = wave >> 1;
    const int m0 = blockIdx.x * 128;
    const int n0 = blockIdx.y * 128;

    f32x4 acc[4][4] = {};
    for (int kb = 0; kb < K; kb += 32) {
#pragma unroll
        for (int rnd = 0; rnd < 2; ++rnd) {
            int c = (rnd * 4 + wave) * 64 + lane;
            int r = c >> 2, seg = c & 3;
            async_copy16(A + (size_t)(m0 + r) * K + kb + seg * 8, As + c * 8);
            async_copy16(BT + (size_t)(n0 + r) * K + kb + seg * 8, Bs + c * 8);
        }
        __syncthreads();
        bf16x8 af[4], bfr[4];
#pragma unroll
        for (int i = 0; i < 4; i++)
            af[i] = *reinterpret_cast<const bf16x8*>(&As[(wm * 64 + i * 16 + l16) * 32 + quad * 8]);
#pragma unroll
        for (int j = 0; j < 4; j++)
            bfr[j] = *reinterpret_cast<const bf16x8*>(&Bs[(wn * 64 + j * 16 + l16) * 32 + quad * 8]);
#pragma unroll
        for (int i = 0; i < 4; i++)
#pragma unroll
            for (int j = 0; j < 4; j++)
                acc[i][j] = __builtin_amdgcn_mfma_f32_16x16x32_bf16(af[i], bfr[j], acc[i][j], 0, 0, 0);
        __syncthreads();
    }
    size_t pbase = ((size_t)(blockIdx.x * 4 + blockIdx.y) * 2 + wm) * 256;
#pragma unroll
    for (int j = 0; j < 4; j++) {
        int f128 = wn * 64 + j * 16 + l16;
        float bv = bias[n0 + f128];
        float s = 0.f, mx = 0.f;
#pragma unroll
        for (int i = 0; i < 4; i++)
#pragma unroll
            for (int r = 0; r < 4; r++) {
                float v = fmaxf(acc[i][j][r] + bv, 0.f);
                s += v;
                mx = fmaxf(mx, v);
            }
        // reduce across the 4 quads (rows) of the wave
        s += __shfl_xor(s, 16);
        s += __shfl_xor(s, 32);
        mx = fmaxf(mx, __shfl_xor(mx, 16));
        mx = fmaxf(mx, __shfl_xor(mx, 32));
        if (quad == 0) {
            partials[pbase + f128] = s;
            partials[pbase + 128 + f128] = mx;
        }
    }
}

// ---------- final pool: combine 8 m-tiles x 2 wave-halves -> mean/max ----------
__global__ __launch_bounds__(256) void k_pool_final(const float* __restrict__ partials,
                                                    float* __restrict__ pooled) {
    int idx = blockIdx.x * 256 + threadIdx.x;  // over 64*512
    int g = idx >> 9, f = idx & 511;
    int by = f >> 7, f128 = f & 127;
    float S = 0.f, M = 0.f;
#pragma unroll
    for (int tile = 0; tile < 8; ++tile) {
        int bx = g * 8 + tile;
#pragma unroll
        for (int wm = 0; wm < 2; ++wm) {
            size_t pbase = ((size_t)(bx * 4 + by) * 2 + wm) * 256;
            S += partials[pbase + f128];
            M = fmaxf(M, partials[pbase + 128 + f128]);
        }
    }
    pooled[g * 1024 + f] = S * (1.0f / 1024.0f);
    pooled[g * 1024 + 512 + f] = M;
}

// ---------- MLP head ----------
__global__ __launch_bounds__(512) void k_mlp1(const float* __restrict__ pooled,
                                              const float* __restrict__ Wm1,
                                              const float* __restrict__ bm1,
                                              float* __restrict__ o) {
    int g = blockIdx.x;
    int f = threadIdx.x;
    __shared__ float hg[1024];
    hg[f] = pooled[g * 1024 + f];
    hg[f + 512] = pooled[g * 1024 + 512 + f];
    __syncthreads();
    float acc = bm1[f];
#pragma unroll 4
    for (int k = 0; k < 1024; ++k)
        acc += hg[k] * Wm1[k * 512 + f];
    o[g * 512 + f] = fmaxf(acc, 0.f);
}

__global__ __launch_bounds__(64) void k_mlp2(const float* __restrict__ h,
                                             const float* __restrict__ Wm2,
                                             const float* __restrict__ bm2,
                                             float* __restrict__ out) {
    int g = blockIdx.x;
    int j = threadIdx.x;
    if (j < 10) {
        float acc = bm2[j];
        for (int k = 0; k < 512; ++k)
            acc += h[g * 512 + k] * Wm2[k * 10 + j];
        out[g * 10 + j] = acc;
    }
}

extern "C" void kernel_launch(void* const* d_in, const int* in_sizes, int n_in,
                              void* d_out, int out_size, void* d_ws, size_t ws_size,
                              hipStream_t stream) {
    const float* x   = (const float*)d_in[0];
    const int*   ei  = (const int*)d_in[1];
    const float* W1  = (const float*)d_in[3];
    const float* b1  = (const float*)d_in[4];
    const float* W2  = (const float*)d_in[5];
    const float* b2  = (const float*)d_in[6];
    const float* W3  = (const float*)d_in[7];
    const float* b3  = (const float*)d_in[8];
    const float* Wm1 = (const float*)d_in[9];
    const float* bm1 = (const float*)d_in[10];
    const float* Wm2 = (const float*)d_in[11];
    const float* bm2 = (const float*)d_in[12];
    float* out = (float*)d_out;

    const int N = in_sizes[0] / 3;  // 65536
    const int E = in_sizes[1] / 2;  // 524288
    const int* row = ei;
    const int* col = ei + E;

    char* ws = (char*)d_ws;
    size_t off = 0;
    auto alloc = [&](size_t bytes) {
        void* p = ws + off;
        off += (bytes + 255) & ~(size_t)255;
        return p;
    };
    int*   cnt      = (int*)alloc((size_t)N * 4);
    int*   rowptr   = (int*)alloc((size_t)N * 4);
    int*   fill     = (int*)alloc((size_t)N * 4);
    float* dinv     = (float*)alloc((size_t)N * 4);
    int2*  adj      = (int2*)alloc((size_t)E * 8);
    float* agg1     = (float*)alloc((size_t)N * 3 * 4);
    bf16*  h1       = (bf16*)alloc((size_t)N * 64 * 2);
    bf16*  agg2     = (bf16*)alloc((size_t)N * 64 * 2);
    bf16*  h2       = (bf16*)alloc((size_t)N * 256 * 2);
    bf16*  agg3     = (bf16*)alloc((size_t)N * 256 * 2);
    bf16*  WT2      = (bf16*)alloc(256 * 64 * 2);
    bf16*  WT3      = (bf16*)alloc(512 * 256 * 2);
    float* partials = (float*)alloc((size_t)512 * 4 * 2 * 256 * 4);  // 4 MB
    float* pooled   = (float*)alloc(64 * 1024 * 4);
    float* m1       = (float*)alloc(64 * 512 * 4);

    // ---- CSR build (once; reused by all 3 layers) ----
    hipMemsetAsync(cnt, 0, (size_t)N * 4, stream);
    hipMemsetAsync(fill, 0, (size_t)N * 4, stream);
    k_count<<<(E + 255) / 256, 256, 0, stream>>>(col, cnt, E);
    k_rsqrt<<<(N + 255) / 256, 256, 0, stream>>>(cnt, dinv, N);
    k_scan<<<1, 1024, 0, stream>>>(cnt, rowptr, N);
    k_scatter<<<(E + 255) / 256, 256, 0, stream>>>(row, col, dinv, rowptr, fill, adj, E);

    // ---- weight prep ----
    k_prep<<<(64 * 256 + 255) / 256, 256, 0, stream>>>(W2, WT2, 64, 256);
    k_prep<<<(256 * 512 + 255) / 256, 256, 0, stream>>>(W3, WT3, 256, 512);

    // ---- layer 1: gather x (F=3), then 3->64 GEMM + bias + relu ----
    k_gather_x<<<(N + 255) / 256, 256, 0, stream>>>(adj, rowptr, cnt, dinv, x, agg1, N);
    k_gemm1<<<(N * 64) / 256, 256, 0, stream>>>(agg1, W1, b1, h1, N);

    // ---- layer 2: gather h1 (F=64), then 64->256 MFMA GEMM + bias + relu ----
    k_gather_pre<64><<<(N * 16) / 256, 256, 0, stream>>>(adj, rowptr, cnt, dinv, h1, agg2, N);
    k_gemm_br<<<dim3(N / 128, 256 / 128), 256, 0, stream>>>(agg2, WT2, b2, h2, N, 256, 64);

    // ---- layer 3: gather h2 (F=256), then 256->512 MFMA GEMM + pool partials ----
    k_gather_pre<256><<<(N * 64) / 256, 256, 0, stream>>>(adj, rowptr, cnt, dinv, h2, agg3, N);
    k_gemm_pool<<<dim3(N / 128, 512 / 128), 256, 0, stream>>>(agg3, WT3, b3, partials, N, 512, 256);
    k_pool_final<<<(64 * 512) / 256, 256, 0, stream>>>(partials, pooled);

    // ---- MLP head ----
    k_mlp1<<<64, 512, 0, stream>>>(pooled, Wm1, bm1, m1);
    k_mlp2<<<64, 64, 0, stream>>>(m1, Wm2, bm2, out);
}

// Round 8
// 316.220 us; speedup vs baseline: 19.7840x; 1.5445x over previous
//
#include <hip/hip_runtime.h>
#include <hip/hip_bf16.h>

typedef __hip_bfloat16 bf16;
typedef short bf16x8 __attribute__((ext_vector_type(8)));
typedef float f32x4 __attribute__((ext_vector_type(4)));

// ---------- helpers ----------
__device__ __forceinline__ float b2f_us(unsigned short u) {
    union { unsigned int i; float f; } c;
    c.i = ((unsigned int)u) << 16;
    return c.f;
}
__device__ __forceinline__ unsigned short f2b_us(float f) {
    bf16 h = __float2bfloat16(f);
    return *reinterpret_cast<unsigned short*>(&h);
}

// async 16B global -> LDS (global_load_lds_dwordx4)
__device__ __forceinline__ void async_copy16(const bf16* g, bf16* l) {
    __builtin_amdgcn_global_load_lds(
        (const __attribute__((address_space(1))) unsigned int*)g,
        (__attribute__((address_space(3))) unsigned int*)l, 16, 0, 0);
}

// ---------- CSR build ----------
__global__ __launch_bounds__(256) void k_count(const int* __restrict__ col,
                                               int* __restrict__ cnt, int E) {
    int e = blockIdx.x * 256 + threadIdx.x;
    if (e < E) atomicAdd(cnt + col[e], 1);
}
__global__ __launch_bounds__(256) void k_rsqrt(const int* __restrict__ cnt,
                                               float* __restrict__ dinv, int N) {
    int i = blockIdx.x * 256 + threadIdx.x;
    if (i < N) dinv[i] = rsqrtf((float)cnt[i] + 1.0f);  // +1 self-loop
}

// ---- hierarchical exclusive scan over N=65536 (256 blocks x 256) ----
__global__ __launch_bounds__(256) void k_scan_a(const int* __restrict__ cnt,
                                                int* __restrict__ bsum) {
    __shared__ int s[256];
    int t = threadIdx.x;
    s[t] = cnt[blockIdx.x * 256 + t];
    __syncthreads();
#pragma unroll
    for (int off = 128; off >= 1; off >>= 1) {
        if (t < off) s[t] += s[t + off];
        __syncthreads();
    }
    if (t == 0) bsum[blockIdx.x] = s[0];
}
__global__ __launch_bounds__(256) void k_scan_b(const int* __restrict__ bsum,
                                                int* __restrict__ boff) {
    __shared__ int s[256];
    int t = threadIdx.x;
    int self = bsum[t];
    s[t] = self;
    __syncthreads();
#pragma unroll
    for (int off = 1; off < 256; off <<= 1) {
        int v = (t >= off) ? s[t - off] : 0;
        __syncthreads();
        s[t] += v;
        __syncthreads();
    }
    boff[t] = s[t] - self;  // exclusive
}
__global__ __launch_bounds__(256) void k_scan_c(const int* __restrict__ cnt,
                                                const int* __restrict__ boff,
                                                int* __restrict__ rowptr) {
    __shared__ int s[256];
    int t = threadIdx.x;
    int base = blockIdx.x * 256;
    int self = cnt[base + t];
    s[t] = self;
    __syncthreads();
#pragma unroll
    for (int off = 1; off < 256; off <<= 1) {
        int v = (t >= off) ? s[t - off] : 0;
        __syncthreads();
        s[t] += v;
        __syncthreads();
    }
    rowptr[base + t] = boff[blockIdx.x] + s[t] - self;  // exclusive
}

__global__ __launch_bounds__(256) void k_scatter(const int* __restrict__ row,
                                                 const int* __restrict__ col,
                                                 const float* __restrict__ dinv,
                                                 const int* __restrict__ rowptr,
                                                 int* __restrict__ fill,
                                                 int2* __restrict__ adj, int E) {
    int e = blockIdx.x * 256 + threadIdx.x;
    if (e >= E) return;
    int r = row[e], c = col[e];
    int pos = rowptr[c] + atomicAdd(fill + c, 1);
    adj[pos] = make_int2(r, __float_as_int(dinv[r]));
}

// ---------- weight prep: W[K,N] f32 -> WT[N,K] bf16 ----------
__global__ __launch_bounds__(256) void k_prep(const float* __restrict__ W,
                                              bf16* __restrict__ WT, int K, int N) {
    int idx = blockIdx.x * 256 + threadIdx.x;
    if (idx >= K * N) return;
    int k = idx / N, n = idx - k * N;
    WT[(size_t)n * K + k] = __float2bfloat16(W[idx]);
}

// ---------- gather on raw x (F=3, f32): agg1 = Ax (normalized, incl. self) ----------
__global__ __launch_bounds__(256) void k_gather_x(const int2* __restrict__ adj,
                                                  const int* __restrict__ rowptr,
                                                  const int* __restrict__ cnt,
                                                  const float* __restrict__ dinv,
                                                  const float* __restrict__ x,
                                                  float* __restrict__ agg1, int N) {
    int n = blockIdx.x * 256 + threadIdx.x;
    if (n >= N) return;
    float d = dinv[n];
    float d2 = d * d;
    float a0 = x[n * 3] * d2, a1 = x[n * 3 + 1] * d2, a2 = x[n * 3 + 2] * d2;
    int beg = rowptr[n], end = beg + cnt[n];
    for (int e = beg; e < end; ++e) {
        int2 ad = adj[e];
        float w = __int_as_float(ad.y) * d;
        a0 += x[ad.x * 3] * w;
        a1 += x[ad.x * 3 + 1] * w;
        a2 += x[ad.x * 3 + 2] * w;
    }
    agg1[n * 3] = a0; agg1[n * 3 + 1] = a1; agg1[n * 3 + 2] = a2;
}

// ---------- layer-1 GEMM: h1 = relu(agg1[N,3] @ W1[3,64] + b1), bf16 out ----------
__global__ __launch_bounds__(256) void k_gemm1(const float* __restrict__ agg1,
                                               const float* __restrict__ W,
                                               const float* __restrict__ bias,
                                               bf16* __restrict__ h1, int M) {
    __shared__ float w[256];
    int t = threadIdx.x;
    if (t < 192) w[t] = W[t];
    if (t >= 192) w[t] = bias[t - 192];
    __syncthreads();
    int idx = blockIdx.x * 256 + t;
    if (idx < M * 64) {
        int n = idx >> 6, f = idx & 63;
        float acc = agg1[n * 3] * w[f] + agg1[n * 3 + 1] * w[64 + f] +
                    agg1[n * 3 + 2] * w[128 + f] + w[192 + f];
        h1[idx] = __float2bfloat16(fmaxf(acc, 0.f));
    }
}

// ---------- CSR gather (bf16 -> bf16, incl. self term; no bias/relu) ----------
template <int F>
__global__ __launch_bounds__(256) void k_gather_pre(const int2* __restrict__ adj,
                                                    const int* __restrict__ rowptr,
                                                    const int* __restrict__ cnt,
                                                    const float* __restrict__ dinv,
                                                    const bf16* __restrict__ h,
                                                    bf16* __restrict__ agg, int N) {
    constexpr int LPN = F / 4;
    constexpr int NPB = 256 / LPN;
    int t = threadIdx.x;
    int node = blockIdx.x * NPB + t / LPN;
    if (node >= N) return;
    int fbase = (t % LPN) * 4;
    float d = dinv[node];
    size_t sbase = (size_t)node * F + fbase;
    ushort4 sp = *reinterpret_cast<const ushort4*>(h + sbase);
    float d2 = d * d;
    float a0 = b2f_us(sp.x) * d2;
    float a1 = b2f_us(sp.y) * d2;
    float a2 = b2f_us(sp.z) * d2;
    float a3 = b2f_us(sp.w) * d2;
    int beg = rowptr[node];
    int end = beg + cnt[node];
    for (int e = beg; e < end; ++e) {
        int2 ad = adj[e];
        float w = __int_as_float(ad.y) * d;
        ushort4 p = *reinterpret_cast<const ushort4*>(h + (size_t)ad.x * F + fbase);
        a0 += b2f_us(p.x) * w;
        a1 += b2f_us(p.y) * w;
        a2 += b2f_us(p.z) * w;
        a3 += b2f_us(p.w) * w;
    }
    ushort4 r;
    r.x = f2b_us(a0); r.y = f2b_us(a1); r.z = f2b_us(a2); r.w = f2b_us(a3);
    *reinterpret_cast<ushort4*>(agg + sbase) = r;
}

// ---------- MFMA GEMM + bias + relu: C = relu(A @ BT^T + b), bf16 out ----------
__global__ __launch_bounds__(256) void k_gemm_br(const bf16* __restrict__ A,
                                                 const bf16* __restrict__ BT,
                                                 const float* __restrict__ bias,
                                                 bf16* __restrict__ C,
                                                 int M, int N, int K) {
    __shared__ bf16 As[128 * 32];
    __shared__ bf16 Bs[128 * 32];
    const int t = threadIdx.x;
    const int wave = t >> 6, lane = t & 63;
    const int quad = lane >> 4, l16 = lane & 15;
    const int wm = wave & 1, wn = wave >> 1;
    const int m0 = blockIdx.x * 128;
    const int n0 = blockIdx.y * 128;

    f32x4 acc[4][4] = {};
    for (int kb = 0; kb < K; kb += 32) {
#pragma unroll
        for (int rnd = 0; rnd < 2; ++rnd) {
            int c = (rnd * 4 + wave) * 64 + lane;
            int r = c >> 2, seg = c & 3;
            async_copy16(A + (size_t)(m0 + r) * K + kb + seg * 8, As + c * 8);
            async_copy16(BT + (size_t)(n0 + r) * K + kb + seg * 8, Bs + c * 8);
        }
        __syncthreads();
        bf16x8 af[4], bfr[4];
#pragma unroll
        for (int i = 0; i < 4; i++)
            af[i] = *reinterpret_cast<const bf16x8*>(&As[(wm * 64 + i * 16 + l16) * 32 + quad * 8]);
#pragma unroll
        for (int j = 0; j < 4; j++)
            bfr[j] = *reinterpret_cast<const bf16x8*>(&Bs[(wn * 64 + j * 16 + l16) * 32 + quad * 8]);
#pragma unroll
        for (int i = 0; i < 4; i++)
#pragma unroll
            for (int j = 0; j < 4; j++)
                acc[i][j] = __builtin_amdgcn_mfma_f32_16x16x32_bf16(af[i], bfr[j], acc[i][j], 0, 0, 0);
        __syncthreads();
    }
#pragma unroll
    for (int j = 0; j < 4; j++) {
        int cn = n0 + wn * 64 + j * 16 + l16;
        float bv = bias[cn];
#pragma unroll
        for (int i = 0; i < 4; i++) {
            int row = m0 + wm * 64 + i * 16 + quad * 4;
#pragma unroll
            for (int r = 0; r < 4; r++)
                C[(size_t)(row + r) * N + cn] = __float2bfloat16(fmaxf(acc[i][j][r] + bv, 0.f));
        }
    }
}

// ---------- MFMA GEMM + bias + relu + per-block pool partials (no atomics) ----------
__global__ __launch_bounds__(256) void k_gemm_pool(const bf16* __restrict__ A,
                                                   const bf16* __restrict__ BT,
                                                   const float* __restrict__ bias,
                                                   float* __restrict__ partials,
                                                   int M, int N, int K) {
    __shared__ bf16 As[128 * 32];
    __shared__ bf16 Bs[128 * 32];
    const int t = threadIdx.x;
    const int wave = t >> 6, lane = t & 63;
    const int quad = lane >> 4, l16 = lane & 15;
    const int wm = wave & 1, wn = wave >> 1;
    const int m0 = blockIdx.x * 128;
    const int n0 = blockIdx.y * 128;

    f32x4 acc[4][4] = {};
    for (int kb = 0; kb < K; kb += 32) {
#pragma unroll
        for (int rnd = 0; rnd < 2; ++rnd) {
            int c = (rnd * 4 + wave) * 64 + lane;
            int r = c >> 2, seg = c & 3;
            async_copy16(A + (size_t)(m0 + r) * K + kb + seg * 8, As + c * 8);
            async_copy16(BT + (size_t)(n0 + r) * K + kb + seg * 8, Bs + c * 8);
        }
        __syncthreads();
        bf16x8 af[4], bfr[4];
#pragma unroll
        for (int i = 0; i < 4; i++)
            af[i] = *reinterpret_cast<const bf16x8*>(&As[(wm * 64 + i * 16 + l16) * 32 + quad * 8]);
#pragma unroll
        for (int j = 0; j < 4; j++)
            bfr[j] = *reinterpret_cast<const bf16x8*>(&Bs[(wn * 64 + j * 16 + l16) * 32 + quad * 8]);
#pragma unroll
        for (int i = 0; i < 4; i++)
#pragma unroll
            for (int j = 0; j < 4; j++)
                acc[i][j] = __builtin_amdgcn_mfma_f32_16x16x32_bf16(af[i], bfr[j], acc[i][j], 0, 0, 0);
        __syncthreads();
    }
    size_t pbase = ((size_t)(blockIdx.x * 4 + blockIdx.y) * 2 + wm) * 256;
#pragma unroll
    for (int j = 0; j < 4; j++) {
        int f128 = wn * 64 + j * 16 + l16;
        float bv = bias[n0 + f128];
        float s = 0.f, mx = 0.f;
#pragma unroll
        for (int i = 0; i < 4; i++)
#pragma unroll
            for (int r = 0; r < 4; r++) {
                float v = fmaxf(acc[i][j][r] + bv, 0.f);
                s += v;
                mx = fmaxf(mx, v);
            }
        s += __shfl_xor(s, 16);
        s += __shfl_xor(s, 32);
        mx = fmaxf(mx, __shfl_xor(mx, 16));
        mx = fmaxf(mx, __shfl_xor(mx, 32));
        if (quad == 0) {
            partials[pbase + f128] = s;
            partials[pbase + 128 + f128] = mx;
        }
    }
}

// ---------- final pool: combine 8 m-tiles x 2 wave-halves -> mean/max ----------
__global__ __launch_bounds__(256) void k_pool_final(const float* __restrict__ partials,
                                                    float* __restrict__ pooled) {
    int idx = blockIdx.x * 256 + threadIdx.x;  // over 64*512
    int g = idx >> 9, f = idx & 511;
    int by = f >> 7, f128 = f & 127;
    float S = 0.f, M = 0.f;
#pragma unroll
    for (int tile = 0; tile < 8; ++tile) {
        int bx = g * 8 + tile;
#pragma unroll
        for (int wm = 0; wm < 2; ++wm) {
            size_t pbase = ((size_t)(bx * 4 + by) * 2 + wm) * 256;
            S += partials[pbase + f128];
            M = fmaxf(M, partials[pbase + 128 + f128]);
        }
    }
    pooled[g * 1024 + f] = S * (1.0f / 1024.0f);
    pooled[g * 1024 + 512 + f] = M;
}

// ---------- MLP head ----------
// grid (64 graphs, 8 f-blocks of 64), 256 thr = 64 features x 4 k-quarters.
__global__ __launch_bounds__(256) void k_mlp1(const float* __restrict__ pooled,
                                              const float* __restrict__ Wm1,
                                              const float* __restrict__ bm1,
                                              float* __restrict__ o) {
    __shared__ float hg[1024];
    __shared__ float red[256];
    int g = blockIdx.x;
    int t = threadIdx.x;
    int f64 = t & 63, kq = t >> 6;
    int f = blockIdx.y * 64 + f64;
#pragma unroll
    for (int i = 0; i < 4; i++) hg[t + i * 256] = pooled[g * 1024 + t + i * 256];
    __syncthreads();
    float acc = 0.f;
    int k0 = kq * 256;
#pragma unroll 8
    for (int k = k0; k < k0 + 256; ++k)
        acc += hg[k] * Wm1[(size_t)k * 512 + f];
    red[t] = acc;
    __syncthreads();
    if (t < 64) {
        float total = red[t] + red[t + 64] + red[t + 128] + red[t + 192] + bm1[f];
        o[g * 512 + f] = fmaxf(total, 0.f);
    }
}

// one 32-lane group per (g, j): 512 thr/block = 16 j-slots (10 used) x 32 lanes.
__global__ __launch_bounds__(512) void k_mlp2(const float* __restrict__ h,
                                              const float* __restrict__ Wm2,
                                              const float* __restrict__ bm2,
                                              float* __restrict__ out) {
    int g = blockIdx.x;
    int t = threadIdx.x;
    int j = t >> 5, lane32 = t & 31;
    float acc = 0.f;
    if (j < 10) {
        int k0 = lane32 * 16;
#pragma unroll
        for (int i = 0; i < 16; ++i)
            acc += h[g * 512 + k0 + i] * Wm2[(size_t)(k0 + i) * 10 + j];
    }
#pragma unroll
    for (int m = 16; m >= 1; m >>= 1) acc += __shfl_xor(acc, m);
    if (j < 10 && lane32 == 0) out[g * 10 + j] = acc + bm2[j];
}

extern "C" void kernel_launch(void* const* d_in, const int* in_sizes, int n_in,
                              void* d_out, int out_size, void* d_ws, size_t ws_size,
                              hipStream_t stream) {
    const float* x   = (const float*)d_in[0];
    const int*   ei  = (const int*)d_in[1];
    const float* W1  = (const float*)d_in[3];
    const float* b1  = (const float*)d_in[4];
    const float* W2  = (const float*)d_in[5];
    const float* b2  = (const float*)d_in[6];
    const float* W3  = (const float*)d_in[7];
    const float* b3  = (const float*)d_in[8];
    const float* Wm1 = (const float*)d_in[9];
    const float* bm1 = (const float*)d_in[10];
    const float* Wm2 = (const float*)d_in[11];
    const float* bm2 = (const float*)d_in[12];
    float* out = (float*)d_out;

    const int N = in_sizes[0] / 3;  // 65536
    const int E = in_sizes[1] / 2;  // 524288
    const int* row = ei;
    const int* col = ei + E;

    char* ws = (char*)d_ws;
    size_t off = 0;
    auto alloc = [&](size_t bytes) {
        void* p = ws + off;
        off += (bytes + 255) & ~(size_t)255;
        return p;
    };
    int*   cnt      = (int*)alloc((size_t)N * 4);
    int*   rowptr   = (int*)alloc((size_t)N * 4);
    int*   fill     = (int*)alloc((size_t)N * 4);
    float* dinv     = (float*)alloc((size_t)N * 4);
    int*   bsum     = (int*)alloc(256 * 4);
    int*   boff     = (int*)alloc(256 * 4);
    int2*  adj      = (int2*)alloc((size_t)E * 8);
    float* agg1     = (float*)alloc((size_t)N * 3 * 4);
    bf16*  h1       = (bf16*)alloc((size_t)N * 64 * 2);
    bf16*  agg2     = (bf16*)alloc((size_t)N * 64 * 2);
    bf16*  h2       = (bf16*)alloc((size_t)N * 256 * 2);
    bf16*  agg3     = (bf16*)alloc((size_t)N * 256 * 2);
    bf16*  WT2      = (bf16*)alloc(256 * 64 * 2);
    bf16*  WT3      = (bf16*)alloc(512 * 256 * 2);
    float* partials = (float*)alloc((size_t)512 * 4 * 2 * 256 * 4);  // 4 MB
    float* pooled   = (float*)alloc(64 * 1024 * 4);
    float* m1       = (float*)alloc(64 * 512 * 4);

    // ---- CSR build (once; reused by all 3 layers) ----
    hipMemsetAsync(cnt, 0, (size_t)N * 4, stream);
    hipMemsetAsync(fill, 0, (size_t)N * 4, stream);
    k_count<<<(E + 255) / 256, 256, 0, stream>>>(col, cnt, E);
    k_rsqrt<<<(N + 255) / 256, 256, 0, stream>>>(cnt, dinv, N);
    k_scan_a<<<256, 256, 0, stream>>>(cnt, bsum);
    k_scan_b<<<1, 256, 0, stream>>>(bsum, boff);
    k_scan_c<<<256, 256, 0, stream>>>(cnt, boff, rowptr);
    k_scatter<<<(E + 255) / 256, 256, 0, stream>>>(row, col, dinv, rowptr, fill, adj, E);

    // ---- weight prep ----
    k_prep<<<(64 * 256 + 255) / 256, 256, 0, stream>>>(W2, WT2, 64, 256);
    k_prep<<<(256 * 512 + 255) / 256, 256, 0, stream>>>(W3, WT3, 256, 512);

    // ---- layer 1: gather x (F=3), then 3->64 GEMM + bias + relu ----
    k_gather_x<<<(N + 255) / 256, 256, 0, stream>>>(adj, rowptr, cnt, dinv, x, agg1, N);
    k_gemm1<<<(N * 64) / 256, 256, 0, stream>>>(agg1, W1, b1, h1, N);

    // ---- layer 2: gather h1 (F=64), then 64->256 MFMA GEMM + bias + relu ----
    k_gather_pre<64><<<(N * 16) / 256, 256, 0, stream>>>(adj, rowptr, cnt, dinv, h1, agg2, N);
    k_gemm_br<<<dim3(N / 128, 256 / 128), 256, 0, stream>>>(agg2, WT2, b2, h2, N, 256, 64);

    // ---- layer 3: gather h2 (F=256), then 256->512 MFMA GEMM + pool partials ----
    k_gather_pre<256><<<(N * 64) / 256, 256, 0, stream>>>(adj, rowptr, cnt, dinv, h2, agg3, N);
    k_gemm_pool<<<dim3(N / 128, 512 / 128), 256, 0, stream>>>(agg3, WT3, b3, partials, N, 512, 256);
    k_pool_final<<<(64 * 512) / 256, 256, 0, stream>>>(partials, pooled);

    // ---- MLP head ----
    k_mlp1<<<dim3(64, 8), 256, 0, stream>>>(pooled, Wm1, bm1, m1);
    k_mlp2<<<64, 512, 0, stream>>>(m1, Wm2, bm2, out);
}

// Round 9
// 284.933 us; speedup vs baseline: 21.9564x; 1.1098x over previous
//
#include <hip/hip_runtime.h>
#include <hip/hip_bf16.h>

typedef __hip_bfloat16 bf16;
typedef short bf16x8 __attribute__((ext_vector_type(8)));
typedef float f32x4 __attribute__((ext_vector_type(4)));

// ---------- helpers ----------
__device__ __forceinline__ float b2f_us(unsigned short u) {
    union { unsigned int i; float f; } c;
    c.i = ((unsigned int)u) << 16;
    return c.f;
}
__device__ __forceinline__ unsigned short f2b_us(float f) {
    bf16 h = __float2bfloat16(f);
    return *reinterpret_cast<unsigned short*>(&h);
}
__device__ __forceinline__ void unpack8(uint4 p, float* f) {
    f[0] = b2f_us(p.x & 0xffff); f[1] = b2f_us(p.x >> 16);
    f[2] = b2f_us(p.y & 0xffff); f[3] = b2f_us(p.y >> 16);
    f[4] = b2f_us(p.z & 0xffff); f[5] = b2f_us(p.z >> 16);
    f[6] = b2f_us(p.w & 0xffff); f[7] = b2f_us(p.w >> 16);
}

// async 16B global -> LDS (global_load_lds_dwordx4)
__device__ __forceinline__ void async_copy16(const bf16* g, bf16* l) {
    __builtin_amdgcn_global_load_lds(
        (const __attribute__((address_space(1))) unsigned int*)g,
        (__attribute__((address_space(3))) unsigned int*)l, 16, 0, 0);
}

// ---------- CSR build ----------
__global__ __launch_bounds__(256) void k_count(const int* __restrict__ col,
                                               int* __restrict__ cnt, int E) {
    int e = blockIdx.x * 256 + threadIdx.x;
    if (e < E) atomicAdd(cnt + col[e], 1);
}
__global__ __launch_bounds__(256) void k_rsqrt(const int* __restrict__ cnt,
                                               float* __restrict__ dinv, int N) {
    int i = blockIdx.x * 256 + threadIdx.x;
    if (i < N) dinv[i] = rsqrtf((float)cnt[i] + 1.0f);  // +1 self-loop
}

// ---- hierarchical exclusive scan over N=65536 (256 blocks x 256) ----
__global__ __launch_bounds__(256) void k_scan_a(const int* __restrict__ cnt,
                                                int* __restrict__ bsum) {
    __shared__ int s[256];
    int t = threadIdx.x;
    s[t] = cnt[blockIdx.x * 256 + t];
    __syncthreads();
#pragma unroll
    for (int off = 128; off >= 1; off >>= 1) {
        if (t < off) s[t] += s[t + off];
        __syncthreads();
    }
    if (t == 0) bsum[blockIdx.x] = s[0];
}
__global__ __launch_bounds__(256) void k_scan_b(const int* __restrict__ bsum,
                                                int* __restrict__ boff) {
    __shared__ int s[256];
    int t = threadIdx.x;
    int self = bsum[t];
    s[t] = self;
    __syncthreads();
#pragma unroll
    for (int off = 1; off < 256; off <<= 1) {
        int v = (t >= off) ? s[t - off] : 0;
        __syncthreads();
        s[t] += v;
        __syncthreads();
    }
    boff[t] = s[t] - self;  // exclusive
}
__global__ __launch_bounds__(256) void k_scan_c(const int* __restrict__ cnt,
                                                const int* __restrict__ boff,
                                                int* __restrict__ rowptr) {
    __shared__ int s[256];
    int t = threadIdx.x;
    int base = blockIdx.x * 256;
    int self = cnt[base + t];
    s[t] = self;
    __syncthreads();
#pragma unroll
    for (int off = 1; off < 256; off <<= 1) {
        int v = (t >= off) ? s[t - off] : 0;
        __syncthreads();
        s[t] += v;
        __syncthreads();
    }
    rowptr[base + t] = boff[blockIdx.x] + s[t] - self;  // exclusive
}

__global__ __launch_bounds__(256) void k_scatter(const int* __restrict__ row,
                                                 const int* __restrict__ col,
                                                 const float* __restrict__ dinv,
                                                 const int* __restrict__ rowptr,
                                                 int* __restrict__ fill,
                                                 int2* __restrict__ adj, int E) {
    int e = blockIdx.x * 256 + threadIdx.x;
    if (e >= E) return;
    int r = row[e], c = col[e];
    int pos = rowptr[c] + atomicAdd(fill + c, 1);
    adj[pos] = make_int2(r, __float_as_int(dinv[r]));
}

// ---------- weight prep: W[K,N] f32 -> WT[N,K] bf16 ----------
__global__ __launch_bounds__(256) void k_prep(const float* __restrict__ W,
                                              bf16* __restrict__ WT, int K, int N) {
    int idx = blockIdx.x * 256 + threadIdx.x;
    if (idx >= K * N) return;
    int k = idx / N, n = idx - k * N;
    WT[(size_t)n * K + k] = __float2bfloat16(W[idx]);
}

// ---------- gather on raw x (F=3, f32): agg1 = Ax (normalized, incl. self) ----------
__global__ __launch_bounds__(256) void k_gather_x(const int2* __restrict__ adj,
                                                  const int* __restrict__ rowptr,
                                                  const int* __restrict__ cnt,
                                                  const float* __restrict__ dinv,
                                                  const float* __restrict__ x,
                                                  float* __restrict__ agg1, int N) {
    int n = blockIdx.x * 256 + threadIdx.x;
    if (n >= N) return;
    float d = dinv[n];
    float d2 = d * d;
    float a0 = x[n * 3] * d2, a1 = x[n * 3 + 1] * d2, a2 = x[n * 3 + 2] * d2;
    int beg = rowptr[n], end = beg + cnt[n];
    for (int e = beg; e < end; ++e) {
        int2 ad = adj[e];
        float w = __int_as_float(ad.y) * d;
        a0 += x[ad.x * 3] * w;
        a1 += x[ad.x * 3 + 1] * w;
        a2 += x[ad.x * 3 + 2] * w;
    }
    agg1[n * 3] = a0; agg1[n * 3 + 1] = a1; agg1[n * 3 + 2] = a2;
}

// ---------- layer-1 GEMM: h1 = relu(agg1[N,3] @ W1[3,64] + b1), bf16 out ----------
__global__ __launch_bounds__(256) void k_gemm1(const float* __restrict__ agg1,
                                               const float* __restrict__ W,
                                               const float* __restrict__ bias,
                                               bf16* __restrict__ h1, int M) {
    __shared__ float w[256];
    int t = threadIdx.x;
    if (t < 192) w[t] = W[t];
    if (t >= 192) w[t] = bias[t - 192];
    __syncthreads();
    int idx = blockIdx.x * 256 + t;
    if (idx < M * 64) {
        int n = idx >> 6, f = idx & 63;
        float acc = agg1[n * 3] * w[f] + agg1[n * 3 + 1] * w[64 + f] +
                    agg1[n * 3 + 2] * w[128 + f] + w[192 + f];
        h1[idx] = __float2bfloat16(fmaxf(acc, 0.f));
    }
}

// ---------- CSR gather (bf16 -> bf16, incl. self; 8 feats/lane, 4-edge unroll) ----------
template <int F>
__global__ __launch_bounds__(256) void k_gather_pre(const int2* __restrict__ adj,
                                                    const int* __restrict__ rowptr,
                                                    const int* __restrict__ cnt,
                                                    const float* __restrict__ dinv,
                                                    const bf16* __restrict__ h,
                                                    bf16* __restrict__ agg, int N) {
    constexpr int LPN = F / 8;           // lanes per node, 8 feats (16B) each
    constexpr int NPB = 256 / LPN;       // nodes per block
    int t = threadIdx.x;
    int node = blockIdx.x * NPB + t / LPN;
    if (node >= N) return;
    int fbase = (t % LPN) * 8;
    float d = dinv[node];
    size_t sbase = (size_t)node * F + fbase;
    uint4 sp = *reinterpret_cast<const uint4*>(h + sbase);
    float a[8];
    unpack8(sp, a);
    float d2 = d * d;
#pragma unroll
    for (int i = 0; i < 8; i++) a[i] *= d2;
    int beg = rowptr[node];
    int end = beg + cnt[node];
    int e = beg;
    for (; e + 3 < end; e += 4) {
        int2 ad0 = adj[e], ad1 = adj[e + 1], ad2 = adj[e + 2], ad3 = adj[e + 3];
        const uint4 p0 = *reinterpret_cast<const uint4*>(h + (size_t)ad0.x * F + fbase);
        const uint4 p1 = *reinterpret_cast<const uint4*>(h + (size_t)ad1.x * F + fbase);
        const uint4 p2 = *reinterpret_cast<const uint4*>(h + (size_t)ad2.x * F + fbase);
        const uint4 p3 = *reinterpret_cast<const uint4*>(h + (size_t)ad3.x * F + fbase);
        float w0 = __int_as_float(ad0.y) * d;
        float w1 = __int_as_float(ad1.y) * d;
        float w2 = __int_as_float(ad2.y) * d;
        float w3 = __int_as_float(ad3.y) * d;
        float f0[8], f1[8], f2[8], f3[8];
        unpack8(p0, f0); unpack8(p1, f1); unpack8(p2, f2); unpack8(p3, f3);
#pragma unroll
        for (int i = 0; i < 8; i++)
            a[i] += f0[i] * w0 + f1[i] * w1 + f2[i] * w2 + f3[i] * w3;
    }
    for (; e < end; ++e) {
        int2 ad = adj[e];
        float w = __int_as_float(ad.y) * d;
        uint4 p = *reinterpret_cast<const uint4*>(h + (size_t)ad.x * F + fbase);
        float f[8];
        unpack8(p, f);
#pragma unroll
        for (int i = 0; i < 8; i++) a[i] += f[i] * w;
    }
    uint4 r;
    r.x = (unsigned)f2b_us(a[0]) | ((unsigned)f2b_us(a[1]) << 16);
    r.y = (unsigned)f2b_us(a[2]) | ((unsigned)f2b_us(a[3]) << 16);
    r.z = (unsigned)f2b_us(a[4]) | ((unsigned)f2b_us(a[5]) << 16);
    r.w = (unsigned)f2b_us(a[6]) | ((unsigned)f2b_us(a[7]) << 16);
    *reinterpret_cast<uint4*>(agg + sbase) = r;
}

// ---------- MFMA GEMM + bias + relu: C = relu(A @ BT^T + b), bf16 out ----------
__global__ __launch_bounds__(256) void k_gemm_br(const bf16* __restrict__ A,
                                                 const bf16* __restrict__ BT,
                                                 const float* __restrict__ bias,
                                                 bf16* __restrict__ C,
                                                 int M, int N, int K) {
    __shared__ bf16 As[128 * 32];
    __shared__ bf16 Bs[128 * 32];
    const int t = threadIdx.x;
    const int wave = t >> 6, lane = t & 63;
    const int quad = lane >> 4, l16 = lane & 15;
    const int wm = wave & 1, wn = wave >> 1;
    const int m0 = blockIdx.x * 128;
    const int n0 = blockIdx.y * 128;

    f32x4 acc[4][4] = {};
    for (int kb = 0; kb < K; kb += 32) {
#pragma unroll
        for (int rnd = 0; rnd < 2; ++rnd) {
            int c = (rnd * 4 + wave) * 64 + lane;
            int r = c >> 2, seg = c & 3;
            async_copy16(A + (size_t)(m0 + r) * K + kb + seg * 8, As + c * 8);
            async_copy16(BT + (size_t)(n0 + r) * K + kb + seg * 8, Bs + c * 8);
        }
        __syncthreads();
        bf16x8 af[4], bfr[4];
#pragma unroll
        for (int i = 0; i < 4; i++)
            af[i] = *reinterpret_cast<const bf16x8*>(&As[(wm * 64 + i * 16 + l16) * 32 + quad * 8]);
#pragma unroll
        for (int j = 0; j < 4; j++)
            bfr[j] = *reinterpret_cast<const bf16x8*>(&Bs[(wn * 64 + j * 16 + l16) * 32 + quad * 8]);
#pragma unroll
        for (int i = 0; i < 4; i++)
#pragma unroll
            for (int j = 0; j < 4; j++)
                acc[i][j] = __builtin_amdgcn_mfma_f32_16x16x32_bf16(af[i], bfr[j], acc[i][j], 0, 0, 0);
        __syncthreads();
    }
#pragma unroll
    for (int j = 0; j < 4; j++) {
        int cn = n0 + wn * 64 + j * 16 + l16;
        float bv = bias[cn];
#pragma unroll
        for (int i = 0; i < 4; i++) {
            int row = m0 + wm * 64 + i * 16 + quad * 4;
#pragma unroll
            for (int r = 0; r < 4; r++)
                C[(size_t)(row + r) * N + cn] = __float2bfloat16(fmaxf(acc[i][j][r] + bv, 0.f));
        }
    }
}

// ---------- MFMA GEMM + bias + relu + per-block pool partials (no atomics) ----------
__global__ __launch_bounds__(256) void k_gemm_pool(const bf16* __restrict__ A,
                                                   const bf16* __restrict__ BT,
                                                   const float* __restrict__ bias,
                                                   float* __restrict__ partials,
                                                   int M, int N, int K) {
    __shared__ bf16 As[128 * 32];
    __shared__ bf16 Bs[128 * 32];
    const int t = threadIdx.x;
    const int wave = t >> 6, lane = t & 63;
    const int quad = lane >> 4, l16 = lane & 15;
    const int wm = wave & 1, wn = wave >> 1;
    const int m0 = blockIdx.x * 128;
    const int n0 = blockIdx.y * 128;

    f32x4 acc[4][4] = {};
    for (int kb = 0; kb < K; kb += 32) {
#pragma unroll
        for (int rnd = 0; rnd < 2; ++rnd) {
            int c = (rnd * 4 + wave) * 64 + lane;
            int r = c >> 2, seg = c & 3;
            async_copy16(A + (size_t)(m0 + r) * K + kb + seg * 8, As + c * 8);
            async_copy16(BT + (size_t)(n0 + r) * K + kb + seg * 8, Bs + c * 8);
        }
        __syncthreads();
        bf16x8 af[4], bfr[4];
#pragma unroll
        for (int i = 0; i < 4; i++)
            af[i] = *reinterpret_cast<const bf16x8*>(&As[(wm * 64 + i * 16 + l16) * 32 + quad * 8]);
#pragma unroll
        for (int j = 0; j < 4; j++)
            bfr[j] = *reinterpret_cast<const bf16x8*>(&Bs[(wn * 64 + j * 16 + l16) * 32 + quad * 8]);
#pragma unroll
        for (int i = 0; i < 4; i++)
#pragma unroll
            for (int j = 0; j < 4; j++)
                acc[i][j] = __builtin_amdgcn_mfma_f32_16x16x32_bf16(af[i], bfr[j], acc[i][j], 0, 0, 0);
        __syncthreads();
    }
    size_t pbase = ((size_t)(blockIdx.x * 4 + blockIdx.y) * 2 + wm) * 256;
#pragma unroll
    for (int j = 0; j < 4; j++) {
        int f128 = wn * 64 + j * 16 + l16;
        float bv = bias[n0 + f128];
        float s = 0.f, mx = 0.f;
#pragma unroll
        for (int i = 0; i < 4; i++)
#pragma unroll
            for (int r = 0; r < 4; r++) {
                float v = fmaxf(acc[i][j][r] + bv, 0.f);
                s += v;
                mx = fmaxf(mx, v);
            }
        s += __shfl_xor(s, 16);
        s += __shfl_xor(s, 32);
        mx = fmaxf(mx, __shfl_xor(mx, 16));
        mx = fmaxf(mx, __shfl_xor(mx, 32));
        if (quad == 0) {
            partials[pbase + f128] = s;
            partials[pbase + 128 + f128] = mx;
        }
    }
}

// ---------- final pool: combine 8 m-tiles x 2 wave-halves -> mean/max ----------
__global__ __launch_bounds__(256) void k_pool_final(const float* __restrict__ partials,
                                                    float* __restrict__ pooled) {
    int idx = blockIdx.x * 256 + threadIdx.x;  // over 64*512
    int g = idx >> 9, f = idx & 511;
    int by = f >> 7, f128 = f & 127;
    float S = 0.f, M = 0.f;
#pragma unroll
    for (int tile = 0; tile < 8; ++tile) {
        int bx = g * 8 + tile;
#pragma unroll
        for (int wm = 0; wm < 2; ++wm) {
            size_t pbase = ((size_t)(bx * 4 + by) * 2 + wm) * 256;
            S += partials[pbase + f128];
            M = fmaxf(M, partials[pbase + 128 + f128]);
        }
    }
    pooled[g * 1024 + f] = S * (1.0f / 1024.0f);
    pooled[g * 1024 + 512 + f] = M;
}

// ---------- MLP head ----------
__global__ __launch_bounds__(256) void k_mlp1(const float* __restrict__ pooled,
                                              const float* __restrict__ Wm1,
                                              const float* __restrict__ bm1,
                                              float* __restrict__ o) {
    __shared__ float hg[1024];
    __shared__ float red[256];
    int g = blockIdx.x;
    int t = threadIdx.x;
    int f64 = t & 63, kq = t >> 6;
    int f = blockIdx.y * 64 + f64;
#pragma unroll
    for (int i = 0; i < 4; i++) hg[t + i * 256] = pooled[g * 1024 + t + i * 256];
    __syncthreads();
    float acc = 0.f;
    int k0 = kq * 256;
#pragma unroll 8
    for (int k = k0; k < k0 + 256; ++k)
        acc += hg[k] * Wm1[(size_t)k * 512 + f];
    red[t] = acc;
    __syncthreads();
    if (t < 64) {
        float total = red[t] + red[t + 64] + red[t + 128] + red[t + 192] + bm1[f];
        o[g * 512 + f] = fmaxf(total, 0.f);
    }
}

__global__ __launch_bounds__(512) void k_mlp2(const float* __restrict__ h,
                                              const float* __restrict__ Wm2,
                                              const float* __restrict__ bm2,
                                              float* __restrict__ out) {
    int g = blockIdx.x;
    int t = threadIdx.x;
    int j = t >> 5, lane32 = t & 31;
    float acc = 0.f;
    if (j < 10) {
        int k0 = lane32 * 16;
#pragma unroll
        for (int i = 0; i < 16; ++i)
            acc += h[g * 512 + k0 + i] * Wm2[(size_t)(k0 + i) * 10 + j];
    }
#pragma unroll
    for (int m = 16; m >= 1; m >>= 1) acc += __shfl_xor(acc, m);
    if (j < 10 && lane32 == 0) out[g * 10 + j] = acc + bm2[j];
}

extern "C" void kernel_launch(void* const* d_in, const int* in_sizes, int n_in,
                              void* d_out, int out_size, void* d_ws, size_t ws_size,
                              hipStream_t stream) {
    const float* x   = (const float*)d_in[0];
    const int*   ei  = (const int*)d_in[1];
    const float* W1  = (const float*)d_in[3];
    const float* b1  = (const float*)d_in[4];
    const float* W2  = (const float*)d_in[5];
    const float* b2  = (const float*)d_in[6];
    const float* W3  = (const float*)d_in[7];
    const float* b3  = (const float*)d_in[8];
    const float* Wm1 = (const float*)d_in[9];
    const float* bm1 = (const float*)d_in[10];
    const float* Wm2 = (const float*)d_in[11];
    const float* bm2 = (const float*)d_in[12];
    float* out = (float*)d_out;

    const int N = in_sizes[0] / 3;  // 65536
    const int E = in_sizes[1] / 2;  // 524288
    const int* row = ei;
    const int* col = ei + E;

    char* ws = (char*)d_ws;
    size_t off = 0;
    auto alloc = [&](size_t bytes) {
        void* p = ws + off;
        off += (bytes + 255) & ~(size_t)255;
        return p;
    };
    int*   cnt      = (int*)alloc((size_t)N * 4);
    int*   rowptr   = (int*)alloc((size_t)N * 4);
    int*   fill     = (int*)alloc((size_t)N * 4);
    float* dinv     = (float*)alloc((size_t)N * 4);
    int*   bsum     = (int*)alloc(256 * 4);
    int*   boff     = (int*)alloc(256 * 4);
    int2*  adj      = (int2*)alloc((size_t)E * 8);
    float* agg1     = (float*)alloc((size_t)N * 3 * 4);
    bf16*  h1       = (bf16*)alloc((size_t)N * 64 * 2);
    bf16*  agg2     = (bf16*)alloc((size_t)N * 64 * 2);
    bf16*  h2       = (bf16*)alloc((size_t)N * 256 * 2);
    bf16*  agg3     = (bf16*)alloc((size_t)N * 256 * 2);
    bf16*  WT2      = (bf16*)alloc(256 * 64 * 2);
    bf16*  WT3      = (bf16*)alloc(512 * 256 * 2);
    float* partials = (float*)alloc((size_t)512 * 4 * 2 * 256 * 4);  // 4 MB
    float* pooled   = (float*)alloc(64 * 1024 * 4);
    float* m1       = (float*)alloc(64 * 512 * 4);

    // ---- CSR build (once; reused by all 3 layers) ----
    hipMemsetAsync(cnt, 0, (size_t)N * 4, stream);
    hipMemsetAsync(fill, 0, (size_t)N * 4, stream);
    k_count<<<(E + 255) / 256, 256, 0, stream>>>(col, cnt, E);
    k_rsqrt<<<(N + 255) / 256, 256, 0, stream>>>(cnt, dinv, N);
    k_scan_a<<<256, 256, 0, stream>>>(cnt, bsum);
    k_scan_b<<<1, 256, 0, stream>>>(bsum, boff);
    k_scan_c<<<256, 256, 0, stream>>>(cnt, boff, rowptr);
    k_scatter<<<(E + 255) / 256, 256, 0, stream>>>(row, col, dinv, rowptr, fill, adj, E);

    // ---- weight prep ----
    k_prep<<<(64 * 256 + 255) / 256, 256, 0, stream>>>(W2, WT2, 64, 256);
    k_prep<<<(256 * 512 + 255) / 256, 256, 0, stream>>>(W3, WT3, 256, 512);

    // ---- layer 1: gather x (F=3), then 3->64 GEMM + bias + relu ----
    k_gather_x<<<(N + 255) / 256, 256, 0, stream>>>(adj, rowptr, cnt, dinv, x, agg1, N);
    k_gemm1<<<(N * 64) / 256, 256, 0, stream>>>(agg1, W1, b1, h1, N);

    // ---- layer 2: gather h1 (F=64, 8 lanes/node), then 64->256 MFMA GEMM ----
    k_gather_pre<64><<<(N * 8) / 256, 256, 0, stream>>>(adj, rowptr, cnt, dinv, h1, agg2, N);
    k_gemm_br<<<dim3(N / 128, 256 / 128), 256, 0, stream>>>(agg2, WT2, b2, h2, N, 256, 64);

    // ---- layer 3: gather h2 (F=256, 32 lanes/node), then 256->512 MFMA + pool ----
    k_gather_pre<256><<<(N * 32) / 256, 256, 0, stream>>>(adj, rowptr, cnt, dinv, h2, agg3, N);
    k_gemm_pool<<<dim3(N / 128, 512 / 128), 256, 0, stream>>>(agg3, WT3, b3, partials, N, 512, 256);
    k_pool_final<<<(64 * 512) / 256, 256, 0, stream>>>(partials, pooled);

    // ---- MLP head ----
    k_mlp1<<<dim3(64, 8), 256, 0, stream>>>(pooled, Wm1, bm1, m1);
    k_mlp2<<<64, 512, 0, stream>>>(m1, Wm2, bm2, out);
}